// Round 1
// baseline (1514.465 us; speedup 1.0000x reference)
//
#include <hip/hip_runtime.h>
#include <math.h>

// Problem constants (BertAttention tree-transformer, B=4, S=1024, H=1024, NH=16)
#define BB 4
#define S 1024
#define H 1024
#define NHD 16
#define DH 64
#define LN_EPS 1e-12f
#define SQ9 3.1622776601683795e-5f   // sqrt(1e-9)

// ---------------- block reduction helpers (blockDim.x == 256) ----------------
__device__ __forceinline__ float block_sum256(float v, float* buf) {
#pragma unroll
  for (int o = 32; o > 0; o >>= 1) v += __shfl_down(v, o);
  if ((threadIdx.x & 63) == 0) buf[threadIdx.x >> 6] = v;
  __syncthreads();
  float r = buf[0] + buf[1] + buf[2] + buf[3];
  __syncthreads();
  return r;
}

__device__ __forceinline__ float block_max256(float v, float* buf) {
#pragma unroll
  for (int o = 32; o > 0; o >>= 1) v = fmaxf(v, __shfl_down(v, o));
  if ((threadIdx.x & 63) == 0) buf[threadIdx.x >> 6] = v;
  __syncthreads();
  float r = fmaxf(fmaxf(buf[0], buf[1]), fmaxf(buf[2], buf[3]));
  __syncthreads();
  return r;
}

// ---------------- LayerNorm: one block per row of H=1024 ----------------
__global__ __launch_bounds__(256) void ln_kernel(
    const float* __restrict__ x, const float* __restrict__ sc,
    const float* __restrict__ bi, float* __restrict__ y) {
  __shared__ float buf[4];
  size_t row = blockIdx.x;
  const float4 xv = reinterpret_cast<const float4*>(x + row * H)[threadIdx.x];
  float s  = xv.x + xv.y + xv.z + xv.w;
  float s2 = xv.x * xv.x + xv.y * xv.y + xv.z * xv.z + xv.w * xv.w;
  s  = block_sum256(s, buf);
  s2 = block_sum256(s2, buf);
  float mu  = s * (1.0f / H);
  float var = s2 * (1.0f / H) - mu * mu;
  float inv = rsqrtf(var + LN_EPS);
  const float4 sv = reinterpret_cast<const float4*>(sc)[threadIdx.x];
  const float4 bv = reinterpret_cast<const float4*>(bi)[threadIdx.x];
  float4 o;
  o.x = (xv.x - mu) * inv * sv.x + bv.x;
  o.y = (xv.y - mu) * inv * sv.y + bv.y;
  o.z = (xv.z - mu) * inv * sv.z + bv.z;
  o.w = (xv.w - mu) * inv * sv.w + bv.w;
  reinterpret_cast<float4*>(y + row * H)[threadIdx.x] = o;
}

// ---------------- generic fp32 tiled GEMM: C = A @ op(B) [+bias][+resid] ----
// BT=1: C[m,n] = sum_k A[m,k]*B[n,k]   (B is N x K row-major)
// BT=0: C[m,n] = sum_k A[m,k]*B[k,n]   (B is K x N row-major)
template <int BT>
__global__ __launch_bounds__(256) void gemm64_kernel(
    const float* __restrict__ A, const float* __restrict__ B,
    const float* __restrict__ bias, const float* __restrict__ resid,
    float* __restrict__ C, int M, int N, int K) {
  __shared__ float As[16][65];
  __shared__ float Bs[16][65];
  int row0 = blockIdx.y * 64, col0 = blockIdx.x * 64;
  int tid = threadIdx.x;
  int tx = tid & 15, ty = tid >> 4;
  int lr = tid >> 2, lc = (tid & 3) << 2;   // 64 rows x 16 k loader
  int kr = tid >> 4, nc = (tid & 15) << 2;  // 16 k x 64 n loader (NN)
  float acc[4][4] = {};
  for (int k0 = 0; k0 < K; k0 += 16) {
    float4 a4 = *reinterpret_cast<const float4*>(A + (size_t)(row0 + lr) * K + k0 + lc);
    As[lc + 0][lr] = a4.x; As[lc + 1][lr] = a4.y; As[lc + 2][lr] = a4.z; As[lc + 3][lr] = a4.w;
    if (BT) {
      float4 b4 = *reinterpret_cast<const float4*>(B + (size_t)(col0 + lr) * K + k0 + lc);
      Bs[lc + 0][lr] = b4.x; Bs[lc + 1][lr] = b4.y; Bs[lc + 2][lr] = b4.z; Bs[lc + 3][lr] = b4.w;
    } else {
      float4 b4 = *reinterpret_cast<const float4*>(B + (size_t)(k0 + kr) * N + col0 + nc);
      Bs[kr][nc + 0] = b4.x; Bs[kr][nc + 1] = b4.y; Bs[kr][nc + 2] = b4.z; Bs[kr][nc + 3] = b4.w;
    }
    __syncthreads();
#pragma unroll
    for (int kk = 0; kk < 16; ++kk) {
      float a[4], b[4];
#pragma unroll
      for (int u = 0; u < 4; ++u) a[u] = As[kk][ty * 4 + u];
#pragma unroll
      for (int u = 0; u < 4; ++u) b[u] = Bs[kk][tx * 4 + u];
#pragma unroll
      for (int ii = 0; ii < 4; ++ii)
#pragma unroll
        for (int jj = 0; jj < 4; ++jj) acc[ii][jj] = fmaf(a[ii], b[jj], acc[ii][jj]);
    }
    __syncthreads();
  }
#pragma unroll
  for (int ii = 0; ii < 4; ++ii) {
    int row = row0 + ty * 4 + ii;
#pragma unroll
    for (int jj = 0; jj < 4; ++jj) {
      int col = col0 + tx * 4 + jj;
      float v = acc[ii][jj];
      if (bias) v += bias[col];
      if (resid) v += resid[(size_t)row * N + col];
      C[(size_t)row * N + col] = v;
    }
  }
}

// ---------------- band dot products for group attention ----------------
// znext[b,i] = z[b,i]·hs[b,i+1], zprev[b,i] = z[b,i]·hs[b,i-1], ebias = gq[b,i]·gbk
__global__ __launch_bounds__(256) void band_dots_kernel(
    const float* __restrict__ z, const float* __restrict__ hs,
    const float* __restrict__ gq, const float* __restrict__ gbk,
    float* __restrict__ znext, float* __restrict__ zprev, float* __restrict__ ebias) {
  __shared__ float buf[4];
  size_t idx = blockIdx.x;  // b*S + i
  int i = (int)(idx & (S - 1));
  const float4 zv = reinterpret_cast<const float4*>(z + idx * H)[threadIdx.x];
  float dn = 0.f, dp = 0.f, e = 0.f;
  if (i < S - 1) {
    const float4 h = reinterpret_cast<const float4*>(hs + (idx + 1) * H)[threadIdx.x];
    dn = zv.x * h.x + zv.y * h.y + zv.z * h.z + zv.w * h.w;
  }
  if (i > 0) {
    const float4 h = reinterpret_cast<const float4*>(hs + (idx - 1) * H)[threadIdx.x];
    dp = zv.x * h.x + zv.y * h.y + zv.z * h.z + zv.w * h.w;
  }
  {
    const float4 g = reinterpret_cast<const float4*>(gq + idx * H)[threadIdx.x];
    const float4 gb = reinterpret_cast<const float4*>(gbk)[threadIdx.x];
    e = g.x * gb.x + g.y * gb.y + g.z * gb.z + g.w * gb.w;
  }
  dn = block_sum256(dn, buf);
  dp = block_sum256(dp, buf);
  e  = block_sum256(e, buf);
  if (threadIdx.x == 0) { znext[idx] = dn; zprev[idx] = dp; ebias[idx] = e; }
}

// ---------------- per-batch band softmax + log prefix scan ----------------
// Produces s_band[b,i] (band value at (i,i+1)) and Cpre[b,m] = sum_{j<m} L_j,
// L_j = log( mix(gp[b,j,j+1], s_band[j]) + 1e-9 ).
__global__ __launch_bounds__(1024) void band_prefix_kernel(
    const float* __restrict__ znext, const float* __restrict__ zprev,
    const float* __restrict__ ebias, const float* __restrict__ gp,
    float* __restrict__ sband, float* __restrict__ Cpre) {
  __shared__ float pd[S];
  __shared__ float scn[S];
  int b = blockIdx.x, i = threadIdx.x;
  size_t idx = (size_t)b * S + i;
  float e_i = ebias[idx];
  float lu = (znext[idx] + e_i) * (1.0f / (float)H);  // score(i, i+1), valid i<S-1
  float ld = (zprev[idx] + e_i) * (1.0f / (float)H);  // score(i, i-1), valid i>0
  float pf, pdn;
  if (i == 0)          { pf = 1.f; pdn = 0.f; }
  else if (i == S - 1) { pf = 0.f; pdn = 1.f; }
  else {
    float m = fmaxf(lu, ld);
    float eu = expf(lu - m), ed = expf(ld - m);
    float inv = 1.f / (eu + ed);
    pf = eu * inv; pdn = ed * inv;
  }
  pd[i] = pdn;
  __syncthreads();
  float sb = 0.f, L = 0.f;
  if (i < S - 1) {
    sb = sqrtf(pf * pd[i + 1] + 1e-9f);
    float gpv = gp[((size_t)b * S + i) * S + (i + 1)];
    float nm = gpv + (1.f - gpv) * sb;
    L = logf(nm + 1e-9f);
  }
  sband[idx] = sb;
  scn[i] = L;
  __syncthreads();
  // Hillis-Steele inclusive scan over 1024
  for (int off = 1; off < S; off <<= 1) {
    float t = (i >= off) ? scn[i - off] : 0.f;
    __syncthreads();
    scn[i] += t;
    __syncthreads();
  }
  Cpre[idx] = (i > 0) ? scn[i - 1] : 0.f;  // exclusive prefix
}

// ---------------- write g_attn and break_prob (one block per (b,i) row) ----
__global__ __launch_bounds__(256) void gattn_write_kernel(
    const float* __restrict__ gp, const float* __restrict__ sband,
    const float* __restrict__ Cpre, float* __restrict__ ga, float* __restrict__ brk) {
  __shared__ float Crow[S];
  __shared__ float Srow[S];
  size_t bi = blockIdx.x;  // b*S + i
  int b = (int)(bi >> 10), i = (int)(bi & (S - 1));
  reinterpret_cast<float4*>(Crow)[threadIdx.x] =
      reinterpret_cast<const float4*>(Cpre + (size_t)b * S)[threadIdx.x];
  reinterpret_cast<float4*>(Srow)[threadIdx.x] =
      reinterpret_cast<const float4*>(sband + (size_t)b * S)[threadIdx.x];
  __syncthreads();
  float Ci = Crow[i];
  size_t rowoff = bi * S;
  const float4 g4 = reinterpret_cast<const float4*>(gp + rowoff)[threadIdx.x];
  const float gparr[4] = {g4.x, g4.y, g4.z, g4.w};
  float go[4], bo_[4];
#pragma unroll
  for (int j = 0; j < 4; ++j) {
    int k = threadIdx.x * 4 + j;
    float gpv = gparr[j];
    float gav;
    if (k == i) {
      gav = gpv + (1.f - gpv) * SQ9;  // diag gets mixed n_attn value
    } else {
      float d = (k > i) ? (Crow[k] - Ci) : (Ci - Crow[k]);
      gav = expf(d) + 1e-9f;
    }
    float sval = (k == i + 1) ? Srow[i] : ((k == i - 1) ? Srow[k] : SQ9);
    go[j]  = gav;
    bo_[j] = gpv + (1.f - gpv) * sval;
  }
  reinterpret_cast<float4*>(ga + rowoff)[threadIdx.x]  = make_float4(go[0], go[1], go[2], go[3]);
  reinterpret_cast<float4*>(brk + rowoff)[threadIdx.x] = make_float4(bo_[0], bo_[1], bo_[2], bo_[3]);
}

// ---------------- attention scores: per (b,h) q_h @ k_h^T / 8, masked ----
__global__ __launch_bounds__(256) void scores_kernel(
    const float* __restrict__ q, const float* __restrict__ k,
    const int* __restrict__ am, float* __restrict__ out) {
  __shared__ float Qs[16][65];
  __shared__ float Ks[16][65];
  int bh = blockIdx.z;
  int b = bh >> 4, h = bh & 15;
  const float* qh = q + (size_t)b * S * H + h * DH;
  const float* kh = k + (size_t)b * S * H + h * DH;
  int row0 = blockIdx.y * 64, col0 = blockIdx.x * 64;
  int tid = threadIdx.x, tx = tid & 15, ty = tid >> 4;
  int lr = tid >> 2, lc = (tid & 3) << 2;
  float acc[4][4] = {};
  for (int k0 = 0; k0 < DH; k0 += 16) {
    float4 a4 = *reinterpret_cast<const float4*>(qh + (size_t)(row0 + lr) * H + k0 + lc);
    Qs[lc + 0][lr] = a4.x; Qs[lc + 1][lr] = a4.y; Qs[lc + 2][lr] = a4.z; Qs[lc + 3][lr] = a4.w;
    float4 b4 = *reinterpret_cast<const float4*>(kh + (size_t)(col0 + lr) * H + k0 + lc);
    Ks[lc + 0][lr] = b4.x; Ks[lc + 1][lr] = b4.y; Ks[lc + 2][lr] = b4.z; Ks[lc + 3][lr] = b4.w;
    __syncthreads();
#pragma unroll
    for (int kk = 0; kk < 16; ++kk) {
      float a[4], bv[4];
#pragma unroll
      for (int u = 0; u < 4; ++u) a[u] = Qs[kk][ty * 4 + u];
#pragma unroll
      for (int u = 0; u < 4; ++u) bv[u] = Ks[kk][tx * 4 + u];
#pragma unroll
      for (int ii = 0; ii < 4; ++ii)
#pragma unroll
        for (int jj = 0; jj < 4; ++jj) acc[ii][jj] = fmaf(a[ii], bv[jj], acc[ii][jj]);
    }
    __syncthreads();
  }
  size_t sbase = ((size_t)b * NHD + h) * S;
#pragma unroll
  for (int ii = 0; ii < 4; ++ii) {
    int row = row0 + ty * 4 + ii;
#pragma unroll
    for (int jj = 0; jj < 4; ++jj) {
      int col = col0 + tx * 4 + jj;
      int keep = am[((size_t)b * S + row) * S + col] | (row == col);
      float v = keep ? acc[ii][jj] * 0.125f : -__builtin_inff();
      out[(sbase + row) * S + col] = v;
    }
  }
}

// ---------------- softmax row stats over S=1024 ----------------
__global__ __launch_bounds__(256) void softmax_stats_kernel(
    const float* __restrict__ scores, float* __restrict__ mx, float* __restrict__ sm) {
  __shared__ float buf[4];
  size_t row = blockIdx.x;
  const float4 v = reinterpret_cast<const float4*>(scores + row * S)[threadIdx.x];
  float m = fmaxf(fmaxf(v.x, v.y), fmaxf(v.z, v.w));
  m = block_max256(m, buf);
  float ss = expf(v.x - m) + expf(v.y - m) + expf(v.z - m) + expf(v.w - m);
  ss = block_sum256(ss, buf);
  if (threadIdx.x == 0) { mx[row] = m; sm[row] = ss; }
}

// ---------------- ctx = (softmax(scores) * g_attn) @ v ----------------
__global__ __launch_bounds__(256) void pv_kernel(
    const float* __restrict__ scores, const float* __restrict__ ga,
    const float* __restrict__ v, const float* __restrict__ mx,
    const float* __restrict__ sm, float* __restrict__ ctx) {
  __shared__ float Ps[16][65];
  __shared__ float Vs[16][65];
  int bh = blockIdx.y;
  int b = bh >> 4, h = bh & 15;
  int row0 = blockIdx.x * 64;
  int tid = threadIdx.x, tx = tid & 15, ty = tid >> 4;
  int lr = tid >> 2, lc = (tid & 3) << 2;
  int kr = tid >> 4, nc = (tid & 15) << 2;
  size_t srow = (((size_t)b * NHD + h) * S + row0 + lr) * S;
  size_t grow = ((size_t)b * S + row0 + lr) * S;
  float mrow = mx[((size_t)b * NHD + h) * S + row0 + lr];
  float isrow = 1.f / sm[((size_t)b * NHD + h) * S + row0 + lr];
  float acc[4][4] = {};
  for (int k0 = 0; k0 < S; k0 += 16) {
    float4 s4 = *reinterpret_cast<const float4*>(scores + srow + k0 + lc);
    float4 g4 = *reinterpret_cast<const float4*>(ga + grow + k0 + lc);
    Ps[lc + 0][lr] = expf(s4.x - mrow) * isrow * g4.x;
    Ps[lc + 1][lr] = expf(s4.y - mrow) * isrow * g4.y;
    Ps[lc + 2][lr] = expf(s4.z - mrow) * isrow * g4.z;
    Ps[lc + 3][lr] = expf(s4.w - mrow) * isrow * g4.w;
    float4 v4 = *reinterpret_cast<const float4*>(v + ((size_t)b * S + k0 + kr) * H + h * DH + nc);
    Vs[kr][nc + 0] = v4.x; Vs[kr][nc + 1] = v4.y; Vs[kr][nc + 2] = v4.z; Vs[kr][nc + 3] = v4.w;
    __syncthreads();
#pragma unroll
    for (int kk = 0; kk < 16; ++kk) {
      float a[4], bv[4];
#pragma unroll
      for (int u = 0; u < 4; ++u) a[u] = Ps[kk][ty * 4 + u];
#pragma unroll
      for (int u = 0; u < 4; ++u) bv[u] = Vs[kk][tx * 4 + u];
#pragma unroll
      for (int ii = 0; ii < 4; ++ii)
#pragma unroll
        for (int jj = 0; jj < 4; ++jj) acc[ii][jj] = fmaf(a[ii], bv[jj], acc[ii][jj]);
    }
    __syncthreads();
  }
#pragma unroll
  for (int ii = 0; ii < 4; ++ii) {
    int row = row0 + ty * 4 + ii;
#pragma unroll
    for (int jj = 0; jj < 4; ++jj) {
      ctx[((size_t)b * S + row) * H + h * DH + tx * 4 + jj] = acc[ii][jj];
    }
  }
}

// ---------------- launch ----------------
extern "C" void kernel_launch(void* const* d_in, const int* in_sizes, int n_in,
                              void* d_out, int out_size, void* d_ws, size_t ws_size,
                              hipStream_t stream) {
  const float* hidden = (const float*)d_in[0];
  const float* gp     = (const float*)d_in[1];
  const int*   am     = (const int*)d_in[2];
  const float* Wq = (const float*)d_in[3];  const float* bq = (const float*)d_in[4];
  const float* Wk = (const float*)d_in[5];  const float* bk = (const float*)d_in[6];
  const float* Wv = (const float*)d_in[7];  const float* bv = (const float*)d_in[8];
  const float* gWq = (const float*)d_in[9]; const float* gbq = (const float*)d_in[10];
  const float* gWk = (const float*)d_in[11];const float* gbk = (const float*)d_in[12];
  const float* glns = (const float*)d_in[13]; const float* glnb = (const float*)d_in[14];
  const float* Wo = (const float*)d_in[15]; const float* bo = (const float*)d_in[16];
  const float* olns = (const float*)d_in[17]; const float* olnb = (const float*)d_in[18];

  float* out    = (float*)d_out;
  float* scores = out + (size_t)BB * S * H;
  float* gattn  = scores + (size_t)BB * NHD * S * S;
  float* brk    = gattn + (size_t)BB * S * S;

  const size_t BIG = (size_t)BB * S * H;  // 4194304
  const size_t BS  = (size_t)BB * S;      // 4096
  const size_t BNS = (size_t)BB * NHD * S;// 65536
  float* w = (float*)d_ws;
  float* buf0 = w;             // hs, later v
  float* buf1 = w + BIG;       // gq, later q, later dense
  float* buf2 = w + 2 * BIG;   // z, later k
  float* buf3 = w + 3 * BIG;   // ctx
  float* znext = w + 4 * BIG;
  float* zprev = znext + BS;
  float* ebias = zprev + BS;
  float* sband = ebias + BS;
  float* Cpre  = sband + BS;
  float* mxa   = Cpre + BS;
  float* sma   = mxa + BNS;

  dim3 blk(256);
  dim3 gemm_grid(H / 64, (BB * S) / 64);        // N=1024, M=4096

  // ---- group attention path ----
  ln_kernel<<<BB * S, blk, 0, stream>>>(hidden, glns, glnb, buf0);                       // hs
  gemm64_kernel<1><<<gemm_grid, blk, 0, stream>>>(buf0, gWq, gbq, nullptr, buf1,
                                                  BB * S, H, H);                          // gq
  gemm64_kernel<0><<<gemm_grid, blk, 0, stream>>>(buf1, gWk, nullptr, nullptr, buf2,
                                                  BB * S, H, H);                          // z
  band_dots_kernel<<<BB * S, blk, 0, stream>>>(buf2, buf0, buf1, gbk, znext, zprev, ebias);
  band_prefix_kernel<<<BB, 1024, 0, stream>>>(znext, zprev, ebias, gp, sband, Cpre);
  gattn_write_kernel<<<BB * S, blk, 0, stream>>>(gp, sband, Cpre, gattn, brk);

  // ---- main attention ----
  gemm64_kernel<1><<<gemm_grid, blk, 0, stream>>>(hidden, Wq, bq, nullptr, buf1,
                                                  BB * S, H, H);                          // q
  gemm64_kernel<1><<<gemm_grid, blk, 0, stream>>>(hidden, Wk, bk, nullptr, buf2,
                                                  BB * S, H, H);                          // k
  gemm64_kernel<1><<<gemm_grid, blk, 0, stream>>>(hidden, Wv, bv, nullptr, buf0,
                                                  BB * S, H, H);                          // v
  scores_kernel<<<dim3(S / 64, S / 64, BB * NHD), blk, 0, stream>>>(buf1, buf2, am, scores);
  softmax_stats_kernel<<<BB * NHD * S, blk, 0, stream>>>(scores, mxa, sma);
  pv_kernel<<<dim3(S / 64, BB * NHD), blk, 0, stream>>>(scores, gattn, buf0, mxa, sma, buf3);

  // ---- output projection + residual + LN ----
  gemm64_kernel<1><<<gemm_grid, blk, 0, stream>>>(buf3, Wo, bo, hidden, buf1,
                                                  BB * S, H, H);                          // dense
  ln_kernel<<<BB * S, blk, 0, stream>>>(buf1, olns, olnb, out);
}

// Round 2
// 435.889 us; speedup vs baseline: 3.4744x; 3.4744x over previous
//
#include <hip/hip_runtime.h>
#include <math.h>

#define BB 4
#define S 1024
#define H 1024
#define NHD 16
#define DH 64
#define LN_EPS 1e-12f
#define SQ9 3.1622776601683795e-5f
#define NEG_INF (-__builtin_inff())

typedef unsigned short u16;
typedef unsigned int u32;
using bfrag = __attribute__((ext_vector_type(8))) short;   // 8 bf16 (MFMA A/B frag)
using f32x4 = __attribute__((ext_vector_type(4))) float;   // MFMA C/D frag

typedef __attribute__((address_space(1))) void void_g;
typedef __attribute__((address_space(3))) void void_l;

__device__ __forceinline__ void gload16(const void* g, void* l) {
  __builtin_amdgcn_global_load_lds((void_g*)g, (void_l*)l, 16, 0, 0);
}

__device__ __forceinline__ u16 f2bf(float f) {
  u32 u = __builtin_bit_cast(u32, f);
  u32 r = (u + 0x7fffu + ((u >> 16) & 1u)) >> 16;
  return (u16)r;
}
__device__ __forceinline__ float bf2f(u32 b) {
  u32 u = b << 16;
  return __builtin_bit_cast(float, u);
}

// ---------------- block reductions (blockDim.x == 256) ----------------
__device__ __forceinline__ float block_sum256(float v, float* buf) {
#pragma unroll
  for (int o = 32; o > 0; o >>= 1) v += __shfl_down(v, o);
  if ((threadIdx.x & 63) == 0) buf[threadIdx.x >> 6] = v;
  __syncthreads();
  float r = buf[0] + buf[1] + buf[2] + buf[3];
  __syncthreads();
  return r;
}

// ---------------- casts ----------------
__global__ __launch_bounds__(256) void cast_kernel(const float* __restrict__ x,
                                                   u16* __restrict__ y, int n4) {
  int i = blockIdx.x * 256 + threadIdx.x;
  if (i < n4) {
    float4 v = reinterpret_cast<const float4*>(x)[i];
    u32 lo = (u32)f2bf(v.x) | ((u32)f2bf(v.y) << 16);
    u32 hi = (u32)f2bf(v.z) | ((u32)f2bf(v.w) << 16);
    reinterpret_cast<uint2*>(y)[i] = make_uint2(lo, hi);
  }
}

// ---------------- LayerNorm (templated output) ----------------
template <typename OutT>
__global__ __launch_bounds__(256) void ln_kernel(
    const float* __restrict__ x, const float* __restrict__ sc,
    const float* __restrict__ bi, OutT* __restrict__ y) {
  __shared__ float buf[4];
  size_t row = blockIdx.x;
  const float4 xv = reinterpret_cast<const float4*>(x + row * H)[threadIdx.x];
  float s  = xv.x + xv.y + xv.z + xv.w;
  float s2 = xv.x * xv.x + xv.y * xv.y + xv.z * xv.z + xv.w * xv.w;
  s  = block_sum256(s, buf);
  s2 = block_sum256(s2, buf);
  float mu  = s * (1.0f / H);
  float var = s2 * (1.0f / H) - mu * mu;
  float inv = rsqrtf(var + LN_EPS);
  const float4 sv = reinterpret_cast<const float4*>(sc)[threadIdx.x];
  const float4 bv = reinterpret_cast<const float4*>(bi)[threadIdx.x];
  float4 o;
  o.x = (xv.x - mu) * inv * sv.x + bv.x;
  o.y = (xv.y - mu) * inv * sv.y + bv.y;
  o.z = (xv.z - mu) * inv * sv.z + bv.z;
  o.w = (xv.w - mu) * inv * sv.w + bv.w;
  if constexpr (sizeof(OutT) == 2) {
    u32 lo = (u32)f2bf(o.x) | ((u32)f2bf(o.y) << 16);
    u32 hi = (u32)f2bf(o.z) | ((u32)f2bf(o.w) << 16);
    reinterpret_cast<uint2*>((u16*)y + row * H)[threadIdx.x] = make_uint2(lo, hi);
  } else {
    reinterpret_cast<float4*>((float*)y + row * H)[threadIdx.x] = o;
  }
}

// ---------------- bf16 MFMA GEMM: C = A @ B^T + bias [+resid] ----------------
// A [M][K] bf16, Bw [N][K] bf16 (weights row-major = B^T form), C [M][N]
// 128x128 tile, BK=64, 4 waves (2x2), double-buffered LDS, global_load_lds
// LDS element (row,kbyte) stored at row*128 + (kbyte ^ ((row&7)<<4))
template <typename OutT, bool HasResid>
__global__ __launch_bounds__(256) void gemm_bt(
    const u16* __restrict__ A, const u16* __restrict__ Bw,
    const float* __restrict__ bias, const float* __restrict__ resid,
    OutT* __restrict__ C, int Kdim, int N) {
  __shared__ __align__(16) u16 Abuf[2][8192];
  __shared__ __align__(16) u16 Bbuf[2][8192];
  int rowBlk = blockIdx.y * 128, colBlk = blockIdx.x * 128;
  int tid = threadIdx.x, wid = tid >> 6, l = tid & 63;
  int dr = l >> 3, sl = l & 7;
  int co = (sl ^ dr) << 3;  // pre-swizzled global column offset (bf16 elems)
  const u16* Ag = A + (size_t)rowBlk * Kdim;
  const u16* Bg = Bw + (size_t)colBlk * Kdim;
  f32x4 acc[4][4];
#pragma unroll
  for (int i = 0; i < 4; ++i)
#pragma unroll
    for (int j = 0; j < 4; ++j) acc[i][j] = (f32x4){0.f, 0.f, 0.f, 0.f};

#pragma unroll
  for (int i = 0; i < 4; ++i) {
    int L = wid * 4 + i;
    gload16(Ag + (size_t)(L * 8 + dr) * Kdim + co, &Abuf[0][L * 512]);
    gload16(Bg + (size_t)(L * 8 + dr) * Kdim + co, &Bbuf[0][L * 512]);
  }
  __syncthreads();
  int wm = wid >> 1, wn = wid & 1;
  int nt = Kdim >> 6;
  int buf = 0;
  int sw = (l & 7) << 4;
  for (int t = 0; t < nt; ++t) {
    if (t + 1 < nt) {
      int k0 = (t + 1) << 6;
#pragma unroll
      for (int i = 0; i < 4; ++i) {
        int L = wid * 4 + i;
        gload16(Ag + (size_t)(L * 8 + dr) * Kdim + k0 + co, &Abuf[buf ^ 1][L * 512]);
        gload16(Bg + (size_t)(L * 8 + dr) * Kdim + k0 + co, &Bbuf[buf ^ 1][L * 512]);
      }
    }
    const char* Ab = (const char*)Abuf[buf];
    const char* Bb = (const char*)Bbuf[buf];
#pragma unroll
    for (int ks = 0; ks < 2; ++ks) {
      int kb = (ks * 64 + ((l >> 4) << 4)) ^ sw;
      bfrag af[4], bf[4];
#pragma unroll
      for (int mi = 0; mi < 4; ++mi)
        af[mi] = *(const bfrag*)(Ab + (wm * 64 + mi * 16 + (l & 15)) * 128 + kb);
#pragma unroll
      for (int ni = 0; ni < 4; ++ni)
        bf[ni] = *(const bfrag*)(Bb + (wn * 64 + ni * 16 + (l & 15)) * 128 + kb);
#pragma unroll
      for (int mi = 0; mi < 4; ++mi)
#pragma unroll
        for (int ni = 0; ni < 4; ++ni)
          acc[mi][ni] = __builtin_amdgcn_mfma_f32_16x16x32_bf16(af[mi], bf[ni], acc[mi][ni], 0, 0, 0);
    }
    __syncthreads();
    buf ^= 1;
  }
#pragma unroll
  for (int mi = 0; mi < 4; ++mi) {
#pragma unroll
    for (int ni = 0; ni < 4; ++ni) {
      int col = colBlk + wn * 64 + ni * 16 + (l & 15);
      float bv = bias[col];
#pragma unroll
      for (int j = 0; j < 4; ++j) {
        int row = rowBlk + wm * 64 + mi * 16 + ((l >> 4) << 2) + j;
        float v = acc[mi][ni][j] + bv;
        if (HasResid) v += resid[(size_t)row * N + col];
        if constexpr (sizeof(OutT) == 2)
          C[(size_t)row * N + col] = (OutT)f2bf(v);
        else
          C[(size_t)row * N + col] = v;
      }
    }
  }
}

// ---------------- band dot products (bf16 gq,gk) ----------------
__global__ __launch_bounds__(256) void band_dots_kernel(
    const u16* __restrict__ gq, const u16* __restrict__ gk,
    float* __restrict__ znext, float* __restrict__ zprev) {
  __shared__ float buf[4];
  size_t idx = blockIdx.x;
  int i = (int)(idx & (S - 1));
  uint2 q2 = reinterpret_cast<const uint2*>(gq + idx * H)[threadIdx.x];
  float q0 = bf2f(q2.x & 0xffff), q1 = bf2f(q2.x >> 16);
  float q2f = bf2f(q2.y & 0xffff), q3 = bf2f(q2.y >> 16);
  float dn = 0.f, dp = 0.f;
  if (i < S - 1) {
    uint2 k2 = reinterpret_cast<const uint2*>(gk + (idx + 1) * H)[threadIdx.x];
    dn = q0 * bf2f(k2.x & 0xffff) + q1 * bf2f(k2.x >> 16) +
         q2f * bf2f(k2.y & 0xffff) + q3 * bf2f(k2.y >> 16);
  }
  if (i > 0) {
    uint2 k2 = reinterpret_cast<const uint2*>(gk + (idx - 1) * H)[threadIdx.x];
    dp = q0 * bf2f(k2.x & 0xffff) + q1 * bf2f(k2.x >> 16) +
         q2f * bf2f(k2.y & 0xffff) + q3 * bf2f(k2.y >> 16);
  }
  dn = block_sum256(dn, buf);
  dp = block_sum256(dp, buf);
  if (threadIdx.x == 0) { znext[idx] = dn; zprev[idx] = dp; }
}

// ---------------- band softmax + log prefix scan (honors attention_mask) ----
__global__ __launch_bounds__(1024) void band_prefix_kernel(
    const float* __restrict__ znext, const float* __restrict__ zprev,
    const int* __restrict__ am, const float* __restrict__ gp,
    float* __restrict__ sband, float* __restrict__ Cpre) {
  __shared__ float pd[S];
  __shared__ float scn[S];
  int b = blockIdx.x, i = threadIdx.x;
  size_t idx = (size_t)b * S + i;
  bool luv = (i < S - 1) && (am[((size_t)b * S + i) * S + i + 1] != 0);
  bool ldv = (i > 0) && (am[((size_t)b * S + i) * S + i - 1] != 0);
  float pf, pdn;
  if (!luv && !ldv) { pf = 0.f; pdn = 0.f; }
  else if (!ldv)    { pf = 1.f; pdn = 0.f; }
  else if (!luv)    { pf = 0.f; pdn = 1.f; }
  else {
    float lu = znext[idx] * (1.0f / (float)H);
    float ld = zprev[idx] * (1.0f / (float)H);
    float m = fmaxf(lu, ld);
    float eu = expf(lu - m), ed = expf(ld - m);
    float inv = 1.f / (eu + ed);
    pf = eu * inv; pdn = ed * inv;
  }
  pd[i] = pdn;
  __syncthreads();
  float sb = 0.f, L = 0.f;
  if (i < S - 1) {
    sb = sqrtf(pf * pd[i + 1] + 1e-9f);
    float gpv = gp[((size_t)b * S + i) * S + (i + 1)];
    float nm = gpv + (1.f - gpv) * sb;
    L = logf(nm + 1e-9f);
  }
  sband[idx] = sb;
  scn[i] = L;
  __syncthreads();
  for (int off = 1; off < S; off <<= 1) {
    float t = (i >= off) ? scn[i - off] : 0.f;
    __syncthreads();
    scn[i] += t;
    __syncthreads();
  }
  Cpre[idx] = (i > 0) ? scn[i - 1] : 0.f;
}

// ---------------- write g_attn and break_prob ----------------
__global__ __launch_bounds__(256) void gattn_write_kernel(
    const float* __restrict__ gp, const float* __restrict__ sband,
    const float* __restrict__ Cpre, float* __restrict__ ga, float* __restrict__ brk) {
  __shared__ float Crow[S];
  __shared__ float Srow[S];
  size_t bi = blockIdx.x;
  int b = (int)(bi >> 10), i = (int)(bi & (S - 1));
  reinterpret_cast<float4*>(Crow)[threadIdx.x] =
      reinterpret_cast<const float4*>(Cpre + (size_t)b * S)[threadIdx.x];
  reinterpret_cast<float4*>(Srow)[threadIdx.x] =
      reinterpret_cast<const float4*>(sband + (size_t)b * S)[threadIdx.x];
  __syncthreads();
  float Ci = Crow[i];
  size_t rowoff = bi * S;
  const float4 g4 = reinterpret_cast<const float4*>(gp + rowoff)[threadIdx.x];
  const float gparr[4] = {g4.x, g4.y, g4.z, g4.w};
  float go[4], bo_[4];
#pragma unroll
  for (int j = 0; j < 4; ++j) {
    int k = threadIdx.x * 4 + j;
    float gpv = gparr[j];
    float gav;
    if (k == i) {
      gav = gpv + (1.f - gpv) * SQ9;
    } else {
      float d = (k > i) ? (Crow[k] - Ci) : (Ci - Crow[k]);
      gav = expf(d) + 1e-9f;
    }
    float sval = (k == i + 1) ? Srow[i] : ((k == i - 1) ? Srow[k] : SQ9);
    go[j]  = gav;
    bo_[j] = gpv + (1.f - gpv) * sval;
  }
  reinterpret_cast<float4*>(ga + rowoff)[threadIdx.x]  = make_float4(go[0], go[1], go[2], go[3]);
  reinterpret_cast<float4*>(brk + rowoff)[threadIdx.x] = make_float4(bo_[0], bo_[1], bo_[2], bo_[3]);
}

// ---------------- V transpose: v[B,S,H] bf16 -> vt[(b*NH+h)*64+d][S] bf16 ----
__global__ __launch_bounds__(256) void transpose_v_kernel(
    const u16* __restrict__ v, u16* __restrict__ vt) {
  __shared__ __align__(16) u16 t[64][72];
  int sb = blockIdx.x, bh = blockIdx.y;
  int b = bh >> 4, h = bh & 15;
  int tid = threadIdx.x;
  int r = tid >> 3, c = (tid & 7) << 3;
#pragma unroll
  for (int p = 0; p < 2; ++p) {
    int row = p * 32 + r;
    uint4 d4 = *reinterpret_cast<const uint4*>(v + ((size_t)b * S + sb * 64 + row) * H + h * 64 + c);
    *reinterpret_cast<uint4*>(&t[row][c]) = d4;
  }
  __syncthreads();
  int d = tid >> 2, sq = (tid & 3) << 4;
  u32 w[8];
#pragma unroll
  for (int x = 0; x < 8; ++x)
    w[x] = (u32)t[sq + 2 * x][d] | ((u32)t[sq + 2 * x + 1][d] << 16);
  u16* dst = vt + ((size_t)bh * 64 + d) * S + sb * 64 + sq;
  reinterpret_cast<uint4*>(dst)[0] = make_uint4(w[0], w[1], w[2], w[3]);
  reinterpret_cast<uint4*>(dst)[1] = make_uint4(w[4], w[5], w[6], w[7]);
}

// ---------------- scores (MFMA) + fused online softmax stats ----------------
// grid (S/64, B*NH); block 256 = 4 waves; wave w owns q-rows qb*64+w*16..+15
__global__ __launch_bounds__(256) void scores_fused_kernel(
    const u16* __restrict__ q, const u16* __restrict__ k, const int* __restrict__ am,
    float* __restrict__ scores, float* __restrict__ mx, float* __restrict__ sm) {
  __shared__ __align__(16) u16 Qt[4096];
  __shared__ __align__(16) u16 Kt[2][4096];
  int qb = blockIdx.x, bh = blockIdx.y;
  int b = bh >> 4, h = bh & 15;
  int tid = threadIdx.x, wid = tid >> 6, l = tid & 63;
  int dr = l >> 3, sl = l & 7;
  int co = (sl ^ dr) << 3;
  const u16* qbase = q + ((size_t)b * S + qb * 64) * H + h * 64;
  const u16* kbase = k + (size_t)b * S * H + h * 64;
#pragma unroll
  for (int i = 0; i < 2; ++i) {
    int L = wid * 2 + i;
    gload16(qbase + (size_t)(L * 8 + dr) * H + co, &Qt[L * 512]);
    gload16(kbase + (size_t)(L * 8 + dr) * H + co, &Kt[0][L * 512]);
  }
  __syncthreads();
  float m_run[4], l_run[4];
#pragma unroll
  for (int j = 0; j < 4; ++j) { m_run[j] = NEG_INF; l_run[j] = 0.f; }
  int buf = 0;
  int sw = (l & 7) << 4;
  int qr = l & 15;
  for (int kt = 0; kt < 16; ++kt) {
    if (kt < 15) {
      const u16* kb2 = kbase + (size_t)((kt + 1) * 64) * H;
#pragma unroll
      for (int i = 0; i < 2; ++i) {
        int L = wid * 2 + i;
        gload16(kb2 + (size_t)(L * 8 + dr) * H + co, &Kt[buf ^ 1][L * 512]);
      }
    }
    f32x4 acc[4];
#pragma unroll
    for (int nb = 0; nb < 4; ++nb) acc[nb] = (f32x4){0.f, 0.f, 0.f, 0.f};
#pragma unroll
    for (int ks = 0; ks < 2; ++ks) {
      int kb = (ks * 64 + ((l >> 4) << 4)) ^ sw;
      bfrag a = *(const bfrag*)((const char*)Qt + (wid * 16 + qr) * 128 + kb);
#pragma unroll
      for (int nb = 0; nb < 4; ++nb) {
        bfrag bv = *(const bfrag*)((const char*)Kt[buf] + (nb * 16 + qr) * 128 + kb);
        acc[nb] = __builtin_amdgcn_mfma_f32_16x16x32_bf16(a, bv, acc[nb], 0, 0, 0);
      }
    }
    float vals[4][4];
    float tm[4] = {NEG_INF, NEG_INF, NEG_INF, NEG_INF};
    int rb = qb * 64 + wid * 16 + ((l >> 4) << 2);
#pragma unroll
    for (int j = 0; j < 4; ++j) {
      int row = rb + j;
      const int* amr = am + ((size_t)b * S + row) * S + kt * 64;
      float* srow = scores + ((size_t)bh * S + row) * S + kt * 64;
#pragma unroll
      for (int nb = 0; nb < 4; ++nb) {
        int col = nb * 16 + (l & 15);
        int colg = kt * 64 + col;
        int keep = amr[col] | (row == colg);
        float v = keep ? acc[nb][j] * 0.125f : NEG_INF;
        vals[nb][j] = v;
        srow[col] = v;
        tm[j] = fmaxf(tm[j], v);
      }
    }
#pragma unroll
    for (int j = 0; j < 4; ++j) {
#pragma unroll
      for (int o = 1; o < 16; o <<= 1) tm[j] = fmaxf(tm[j], __shfl_xor(tm[j], o));
    }
#pragma unroll
    for (int j = 0; j < 4; ++j) {
      if (tm[j] > NEG_INF) {
        float mn = fmaxf(m_run[j], tm[j]);
        float sc = expf(m_run[j] - mn);
        float ss = expf(vals[0][j] - mn) + expf(vals[1][j] - mn) +
                   expf(vals[2][j] - mn) + expf(vals[3][j] - mn);
#pragma unroll
        for (int o = 1; o < 16; o <<= 1) ss += __shfl_xor(ss, o);
        l_run[j] = l_run[j] * sc + ss;
        m_run[j] = mn;
      }
    }
    __syncthreads();
    buf ^= 1;
  }
  if ((l & 15) == 0) {
    int rb = qb * 64 + wid * 16 + ((l >> 4) << 2);
#pragma unroll
    for (int j = 0; j < 4; ++j) {
      mx[(size_t)bh * S + rb + j] = m_run[j];
      sm[(size_t)bh * S + rb + j] = l_run[j];
    }
  }
}

// ---------------- PV (MFMA): ctx = (softmax(scores)*ga) @ V -> bf16 ----------
__global__ __launch_bounds__(256) void pv_fused_kernel(
    const float* __restrict__ scores, const float* __restrict__ ga,
    const u16* __restrict__ vt, const float* __restrict__ mx, const float* __restrict__ sm,
    u16* __restrict__ ctx) {
  __shared__ __align__(16) u16 Pt[4096];
  __shared__ __align__(16) u16 Vtl[4096];
  __shared__ float mrow[64], irow[64];
  int qb = blockIdx.x, bh = blockIdx.y;
  int b = bh >> 4, h = bh & 15;
  int tid = threadIdx.x, wid = tid >> 6, l = tid & 63;
  if (tid < 64) {
    mrow[tid] = mx[(size_t)bh * S + qb * 64 + tid];
    irow[tid] = 1.f / sm[(size_t)bh * S + qb * 64 + tid];
  }
  __syncthreads();
  int dr = l >> 3, sl = l & 7;
  int co = (sl ^ dr) << 3;
  const u16* vtb = vt + (size_t)bh * 64 * S;
  int pr = tid >> 2, cg = (tid & 3) << 4;
  size_t srb = ((size_t)bh * S + qb * 64 + pr) * S;
  size_t grb = ((size_t)b * S + qb * 64 + pr) * S;
  int psw = (pr & 7) << 4;
  f32x4 acc[4];
#pragma unroll
  for (int nb = 0; nb < 4; ++nb) acc[nb] = (f32x4){0.f, 0.f, 0.f, 0.f};
  for (int kt = 0; kt < 16; ++kt) {
#pragma unroll
    for (int i = 0; i < 2; ++i) {
      int L = wid * 2 + i;
      gload16(vtb + (size_t)(L * 8 + dr) * S + kt * 64 + co, &Vtl[L * 512]);
    }
    float mr = mrow[pr], ir = irow[pr];
    u32 w[8];
#pragma unroll
    for (int c4 = 0; c4 < 4; ++c4) {
      float4 sv = *reinterpret_cast<const float4*>(scores + srb + kt * 64 + cg + c4 * 4);
      float4 gv = *reinterpret_cast<const float4*>(ga + grb + kt * 64 + cg + c4 * 4);
      u16 p0 = f2bf(expf(sv.x - mr) * ir * gv.x);
      u16 p1 = f2bf(expf(sv.y - mr) * ir * gv.y);
      u16 p2 = f2bf(expf(sv.z - mr) * ir * gv.z);
      u16 p3 = f2bf(expf(sv.w - mr) * ir * gv.w);
      w[c4 * 2]     = (u32)p0 | ((u32)p1 << 16);
      w[c4 * 2 + 1] = (u32)p2 | ((u32)p3 << 16);
    }
    char* pt = (char*)Pt + pr * 128;
    *reinterpret_cast<uint4*>(pt + ((cg * 2) ^ psw))      = make_uint4(w[0], w[1], w[2], w[3]);
    *reinterpret_cast<uint4*>(pt + ((cg * 2 + 16) ^ psw)) = make_uint4(w[4], w[5], w[6], w[7]);
    __syncthreads();
    int sw = (l & 7) << 4;
#pragma unroll
    for (int ks = 0; ks < 2; ++ks) {
      int kb = (ks * 64 + ((l >> 4) << 4)) ^ sw;
      bfrag a = *(const bfrag*)((const char*)Pt + (wid * 16 + (l & 15)) * 128 + kb);
#pragma unroll
      for (int nb = 0; nb < 4; ++nb) {
        bfrag bv = *(const bfrag*)((const char*)Vtl + (nb * 16 + (l & 15)) * 128 + kb);
        acc[nb] = __builtin_amdgcn_mfma_f32_16x16x32_bf16(a, bv, acc[nb], 0, 0, 0);
      }
    }
    __syncthreads();
  }
  int rb = qb * 64 + wid * 16 + ((l >> 4) << 2);
#pragma unroll
  for (int nb = 0; nb < 4; ++nb) {
    int d = nb * 16 + (l & 15);
#pragma unroll
    for (int j = 0; j < 4; ++j)
      ctx[((size_t)b * S + rb + j) * H + h * 64 + d] = f2bf(acc[nb][j]);
  }
}

// ---------------- launch ----------------
extern "C" void kernel_launch(void* const* d_in, const int* in_sizes, int n_in,
                              void* d_out, int out_size, void* d_ws, size_t ws_size,
                              hipStream_t stream) {
  const float* hidden = (const float*)d_in[0];
  const float* gp     = (const float*)d_in[1];
  const int*   am     = (const int*)d_in[2];
  const float* Wq = (const float*)d_in[3];  const float* bq = (const float*)d_in[4];
  const float* Wk = (const float*)d_in[5];  const float* bk = (const float*)d_in[6];
  const float* Wv = (const float*)d_in[7];  const float* bv = (const float*)d_in[8];
  const float* gWq = (const float*)d_in[9]; const float* gbq = (const float*)d_in[10];
  const float* gWk = (const float*)d_in[11];const float* gbk = (const float*)d_in[12];
  const float* glns = (const float*)d_in[13]; const float* glnb = (const float*)d_in[14];
  const float* Wo = (const float*)d_in[15]; const float* bo = (const float*)d_in[16];
  const float* olns = (const float*)d_in[17]; const float* olnb = (const float*)d_in[18];

  float* out    = (float*)d_out;
  float* scores = out + (size_t)BB * S * H;
  float* gattn  = scores + (size_t)BB * NHD * S * S;
  float* brk    = gattn + (size_t)BB * S * S;

  const size_t MB = 1u << 20;
  char* w = (char*)d_ws;
  u16* Wqbf  = (u16*)(w);
  u16* Wkbf  = (u16*)(w + 2 * MB);
  u16* Wvbf  = (u16*)(w + 4 * MB);
  u16* Wobf  = (u16*)(w + 6 * MB);
  u16* gWqbf = (u16*)(w + 8 * MB);
  u16* gWkbf = (u16*)(w + 10 * MB);
  u16* hbf   = (u16*)(w + 12 * MB);
  u16* hsbf  = (u16*)(w + 20 * MB);   // later: qbf (after gq/gk GEMMs)
  u16* qbf   = hsbf;
  u16* ctxbf = hsbf;                  // after scores kernel, qbf slot is free
  u16* kbf   = (u16*)(w + 28 * MB);
  u16* gqbf  = (u16*)(w + 36 * MB);   // later: vbf
  u16* vbf   = gqbf;
  u16* gkbf  = (u16*)(w + 44 * MB);   // later: vt
  u16* vtb   = gkbf;
  float* densef = (float*)(w + 36 * MB);  // after transpose+pv, gq/gk slots free
  float* mxa = (float*)(w + 52 * MB);
  float* sma = (float*)(w + 52 * MB + 256 * 1024);
  float* znext  = (float*)(w + 53 * MB);
  float* zprev  = znext + BB * S;
  float* sbandA = zprev + BB * S;
  float* CpreA  = sbandA + BB * S;

  dim3 blk(256);
  dim3 ggrid(H / 128, (BB * S) / 128);  // (8, 32)
  dim3 agrid(S / 64, BB * NHD);         // (16, 64)

  // casts
  cast_kernel<<<1024, blk, 0, stream>>>(Wq, Wqbf, (H * H) / 4);
  cast_kernel<<<1024, blk, 0, stream>>>(Wk, Wkbf, (H * H) / 4);
  cast_kernel<<<1024, blk, 0, stream>>>(Wv, Wvbf, (H * H) / 4);
  cast_kernel<<<1024, blk, 0, stream>>>(Wo, Wobf, (H * H) / 4);
  cast_kernel<<<1024, blk, 0, stream>>>(gWq, gWqbf, (H * H) / 4);
  cast_kernel<<<1024, blk, 0, stream>>>(gWk, gWkbf, (H * H) / 4);
  cast_kernel<<<4096, blk, 0, stream>>>(hidden, hbf, (BB * S * H) / 4);

  // ---- group attention path ----
  ln_kernel<u16><<<BB * S, blk, 0, stream>>>(hidden, glns, glnb, hsbf);
  gemm_bt<u16, false><<<ggrid, blk, 0, stream>>>(hsbf, gWqbf, gbq, nullptr, gqbf, H, H);
  gemm_bt<u16, false><<<ggrid, blk, 0, stream>>>(hsbf, gWkbf, gbk, nullptr, gkbf, H, H);
  band_dots_kernel<<<BB * S, blk, 0, stream>>>(gqbf, gkbf, znext, zprev);
  band_prefix_kernel<<<BB, 1024, 0, stream>>>(znext, zprev, am, gp, sbandA, CpreA);
  gattn_write_kernel<<<BB * S, blk, 0, stream>>>(gp, sbandA, CpreA, gattn, brk);

  // ---- main attention ----
  gemm_bt<u16, false><<<ggrid, blk, 0, stream>>>(hbf, Wqbf, bq, nullptr, qbf, H, H);
  gemm_bt<u16, false><<<ggrid, blk, 0, stream>>>(hbf, Wkbf, bk, nullptr, kbf, H, H);
  gemm_bt<u16, false><<<ggrid, blk, 0, stream>>>(hbf, Wvbf, bv, nullptr, vbf, H, H);
  transpose_v_kernel<<<agrid, blk, 0, stream>>>(vbf, vtb);
  scores_fused_kernel<<<agrid, blk, 0, stream>>>(qbf, kbf, am, scores, mxa, sma);
  pv_fused_kernel<<<agrid, blk, 0, stream>>>(scores, gattn, vtb, mxa, sma, ctxbf);

  // ---- output projection + residual + LN ----
  gemm_bt<float, true><<<ggrid, blk, 0, stream>>>(ctxbf, Wobf, bo, hidden, densef, H, H);
  ln_kernel<float><<<BB * S, blk, 0, stream>>>(densef, olns, olnb, out);
}

// Round 4
// 276.158 us; speedup vs baseline: 5.4840x; 1.5784x over previous
//
#include <hip/hip_runtime.h>
#include <math.h>

#define BB 4
#define S 1024
#define H 1024
#define NHD 16
#define DH 64
#define LN_EPS 1e-12f
#define SQ9 3.1622776601683795e-5f
#define NEG_INF (-__builtin_inff())

typedef unsigned short u16;
typedef unsigned int u32;
using bfrag = __attribute__((ext_vector_type(8))) short;   // 8 bf16 (MFMA A/B frag)
using f32x4 = __attribute__((ext_vector_type(4))) float;   // MFMA C/D frag

typedef __attribute__((address_space(1))) void void_g;
typedef __attribute__((address_space(3))) void void_l;

__device__ __forceinline__ void gload16(const void* g, void* l) {
  __builtin_amdgcn_global_load_lds((void_g*)g, (void_l*)l, 16, 0, 0);
}

__device__ __forceinline__ u16 f2bf(float f) {
  u32 u = __builtin_bit_cast(u32, f);
  u32 r = (u + 0x7fffu + ((u >> 16) & 1u)) >> 16;
  return (u16)r;
}
__device__ __forceinline__ float bf2f(u32 b) {
  u32 u = b << 16;
  return __builtin_bit_cast(float, u);
}

// ---------------- block reductions (blockDim.x == 256) ----------------
__device__ __forceinline__ float block_sum256(float v, float* buf) {
#pragma unroll
  for (int o = 32; o > 0; o >>= 1) v += __shfl_down(v, o);
  if ((threadIdx.x & 63) == 0) buf[threadIdx.x >> 6] = v;
  __syncthreads();
  float r = buf[0] + buf[1] + buf[2] + buf[3];
  __syncthreads();
  return r;
}

// ---------------- fused cast of all weights + hidden to bf16 ----------------
// dst layout (u16): [Wq|Wk|Wv][gWq|gWk][Wo][hidden] contiguous
__global__ __launch_bounds__(256) void cast_all_kernel(
    const float* __restrict__ Wq, const float* __restrict__ Wk, const float* __restrict__ Wv,
    const float* __restrict__ gWq, const float* __restrict__ gWk, const float* __restrict__ Wo,
    const float* __restrict__ hidden, u16* __restrict__ dst) {
  const int WQ = (H * H) / 4;  // 262144 float4 per weight
  int i = blockIdx.x * 256 + threadIdx.x;
  const float* src; int off;
  if      (i < 1 * WQ) { src = Wq;  off = 0; }
  else if (i < 2 * WQ) { src = Wk;  off = 1 * WQ; }
  else if (i < 3 * WQ) { src = Wv;  off = 2 * WQ; }
  else if (i < 4 * WQ) { src = gWq; off = 3 * WQ; }
  else if (i < 5 * WQ) { src = gWk; off = 4 * WQ; }
  else if (i < 6 * WQ) { src = Wo;  off = 5 * WQ; }
  else                 { src = hidden; off = 6 * WQ; }
  float4 v = reinterpret_cast<const float4*>(src)[i - off];
  u32 lo = (u32)f2bf(v.x) | ((u32)f2bf(v.y) << 16);
  u32 hi = (u32)f2bf(v.z) | ((u32)f2bf(v.w) << 16);
  reinterpret_cast<uint2*>(dst)[i] = make_uint2(lo, hi);
}

// ---------------- pack attention mask into bits ----------------
__global__ __launch_bounds__(256) void pack_mask_kernel(const int* __restrict__ am,
                                                        u32* __restrict__ amb) {
  size_t t = (size_t)blockIdx.x * 256 + threadIdx.x;
  int v = am[t] != 0;
  unsigned long long m = __ballot(v);
  int lane = threadIdx.x & 63;
  if (lane == 0)       amb[t >> 5] = (u32)m;
  else if (lane == 32) amb[t >> 5] = (u32)(m >> 32);
}

// ---------------- LayerNorm (templated output) ----------------
template <typename OutT>
__global__ __launch_bounds__(256) void ln_kernel(
    const float* __restrict__ x, const float* __restrict__ sc,
    const float* __restrict__ bi, OutT* __restrict__ y) {
  __shared__ float buf[4];
  size_t row = blockIdx.x;
  const float4 xv = reinterpret_cast<const float4*>(x + row * H)[threadIdx.x];
  float s  = xv.x + xv.y + xv.z + xv.w;
  float s2 = xv.x * xv.x + xv.y * xv.y + xv.z * xv.z + xv.w * xv.w;
  s  = block_sum256(s, buf);
  s2 = block_sum256(s2, buf);
  float mu  = s * (1.0f / H);
  float var = s2 * (1.0f / H) - mu * mu;
  float inv = rsqrtf(var + LN_EPS);
  const float4 sv = reinterpret_cast<const float4*>(sc)[threadIdx.x];
  const float4 bv = reinterpret_cast<const float4*>(bi)[threadIdx.x];
  float4 o;
  o.x = (xv.x - mu) * inv * sv.x + bv.x;
  o.y = (xv.y - mu) * inv * sv.y + bv.y;
  o.z = (xv.z - mu) * inv * sv.z + bv.z;
  o.w = (xv.w - mu) * inv * sv.w + bv.w;
  if constexpr (sizeof(OutT) == 2) {
    u32 lo = (u32)f2bf(o.x) | ((u32)f2bf(o.y) << 16);
    u32 hi = (u32)f2bf(o.z) | ((u32)f2bf(o.w) << 16);
    reinterpret_cast<uint2*>((u16*)y + row * H)[threadIdx.x] = make_uint2(lo, hi);
  } else {
    reinterpret_cast<float4*>((float*)y + row * H)[threadIdx.x] = o;
  }
}

// ---------------- bf16 MFMA GEMM (multi-output): C_i = A @ Bcat_i^T + bias_i --
__global__ __launch_bounds__(256) void gemm_bt3(
    const u16* __restrict__ A, const u16* __restrict__ Bcat,
    const float* __restrict__ b0, const float* __restrict__ b1, const float* __restrict__ b2,
    u16* __restrict__ o0, u16* __restrict__ o1, u16* __restrict__ o2) {
  __shared__ __align__(16) u16 Abuf[2][8192];
  __shared__ __align__(16) u16 Bbuf[2][8192];
  const int Kdim = H;
  int rowBlk = blockIdx.y * 128, colBlk = blockIdx.x * 128;
  int tid = threadIdx.x, wid = tid >> 6, l = tid & 63;
  int dr = l >> 3, sl = l & 7;
  int co = (sl ^ dr) << 3;
  const u16* Ag = A + (size_t)rowBlk * Kdim;
  const u16* Bg = Bcat + (size_t)colBlk * Kdim;
  f32x4 acc[4][4];
#pragma unroll
  for (int i = 0; i < 4; ++i)
#pragma unroll
    for (int j = 0; j < 4; ++j) acc[i][j] = (f32x4){0.f, 0.f, 0.f, 0.f};
#pragma unroll
  for (int i = 0; i < 4; ++i) {
    int L = wid * 4 + i;
    gload16(Ag + (size_t)(L * 8 + dr) * Kdim + co, &Abuf[0][L * 512]);
    gload16(Bg + (size_t)(L * 8 + dr) * Kdim + co, &Bbuf[0][L * 512]);
  }
  __syncthreads();
  int wm = wid >> 1, wn = wid & 1;
  const int nt = Kdim >> 6;
  int buf = 0;
  int sw = (l & 7) << 4;
  for (int t = 0; t < nt; ++t) {
    if (t + 1 < nt) {
      int k0 = (t + 1) << 6;
#pragma unroll
      for (int i = 0; i < 4; ++i) {
        int L = wid * 4 + i;
        gload16(Ag + (size_t)(L * 8 + dr) * Kdim + k0 + co, &Abuf[buf ^ 1][L * 512]);
        gload16(Bg + (size_t)(L * 8 + dr) * Kdim + k0 + co, &Bbuf[buf ^ 1][L * 512]);
      }
    }
    const char* Ab = (const char*)Abuf[buf];
    const char* Bb = (const char*)Bbuf[buf];
#pragma unroll
    for (int ks = 0; ks < 2; ++ks) {
      int kb = (ks * 64 + ((l >> 4) << 4)) ^ sw;
      bfrag af[4], bfv[4];
#pragma unroll
      for (int mi = 0; mi < 4; ++mi)
        af[mi] = *(const bfrag*)(Ab + (wm * 64 + mi * 16 + (l & 15)) * 128 + kb);
#pragma unroll
      for (int ni = 0; ni < 4; ++ni)
        bfv[ni] = *(const bfrag*)(Bb + (wn * 64 + ni * 16 + (l & 15)) * 128 + kb);
#pragma unroll
      for (int mi = 0; mi < 4; ++mi)
#pragma unroll
        for (int ni = 0; ni < 4; ++ni)
          acc[mi][ni] = __builtin_amdgcn_mfma_f32_16x16x32_bf16(af[mi], bfv[ni], acc[mi][ni], 0, 0, 0);
    }
    __syncthreads();
    buf ^= 1;
  }
  int which = colBlk >> 10;
  const float* bias = (which == 0) ? b0 : (which == 1) ? b1 : b2;
  u16* O = (which == 0) ? o0 : (which == 1) ? o1 : o2;
#pragma unroll
  for (int mi = 0; mi < 4; ++mi) {
#pragma unroll
    for (int ni = 0; ni < 4; ++ni) {
      int col = (colBlk + wn * 64 + ni * 16 + (l & 15)) & 1023;
      float bv = bias[col];
#pragma unroll
      for (int j = 0; j < 4; ++j) {
        int row = rowBlk + wm * 64 + mi * 16 + ((l >> 4) << 2) + j;
        O[(size_t)row * H + col] = f2bf(acc[mi][ni][j] + bv);
      }
    }
  }
}

// ---------------- dense: C = A @ B^T + bias + resid (fp32 out) ----------------
__global__ __launch_bounds__(256) void gemm_dense(
    const u16* __restrict__ A, const u16* __restrict__ Bw,
    const float* __restrict__ bias, const float* __restrict__ resid,
    float* __restrict__ C) {
  __shared__ __align__(16) u16 Abuf[2][8192];
  __shared__ __align__(16) u16 Bbuf[2][8192];
  const int Kdim = H;
  int rowBlk = blockIdx.y * 128, colBlk = blockIdx.x * 128;
  int tid = threadIdx.x, wid = tid >> 6, l = tid & 63;
  int dr = l >> 3, sl = l & 7;
  int co = (sl ^ dr) << 3;
  const u16* Ag = A + (size_t)rowBlk * Kdim;
  const u16* Bg = Bw + (size_t)colBlk * Kdim;
  f32x4 acc[4][4];
#pragma unroll
  for (int i = 0; i < 4; ++i)
#pragma unroll
    for (int j = 0; j < 4; ++j) acc[i][j] = (f32x4){0.f, 0.f, 0.f, 0.f};
#pragma unroll
  for (int i = 0; i < 4; ++i) {
    int L = wid * 4 + i;
    gload16(Ag + (size_t)(L * 8 + dr) * Kdim + co, &Abuf[0][L * 512]);
    gload16(Bg + (size_t)(L * 8 + dr) * Kdim + co, &Bbuf[0][L * 512]);
  }
  __syncthreads();
  int wm = wid >> 1, wn = wid & 1;
  const int nt = Kdim >> 6;
  int buf = 0;
  int sw = (l & 7) << 4;
  for (int t = 0; t < nt; ++t) {
    if (t + 1 < nt) {
      int k0 = (t + 1) << 6;
#pragma unroll
      for (int i = 0; i < 4; ++i) {
        int L = wid * 4 + i;
        gload16(Ag + (size_t)(L * 8 + dr) * Kdim + k0 + co, &Abuf[buf ^ 1][L * 512]);
        gload16(Bg + (size_t)(L * 8 + dr) * Kdim + k0 + co, &Bbuf[buf ^ 1][L * 512]);
      }
    }
    const char* Ab = (const char*)Abuf[buf];
    const char* Bb = (const char*)Bbuf[buf];
#pragma unroll
    for (int ks = 0; ks < 2; ++ks) {
      int kb = (ks * 64 + ((l >> 4) << 4)) ^ sw;
      bfrag af[4], bfv[4];
#pragma unroll
      for (int mi = 0; mi < 4; ++mi)
        af[mi] = *(const bfrag*)(Ab + (wm * 64 + mi * 16 + (l & 15)) * 128 + kb);
#pragma unroll
      for (int ni = 0; ni < 4; ++ni)
        bfv[ni] = *(const bfrag*)(Bb + (wn * 64 + ni * 16 + (l & 15)) * 128 + kb);
#pragma unroll
      for (int mi = 0; mi < 4; ++mi)
#pragma unroll
        for (int ni = 0; ni < 4; ++ni)
          acc[mi][ni] = __builtin_amdgcn_mfma_f32_16x16x32_bf16(af[mi], bfv[ni], acc[mi][ni], 0, 0, 0);
    }
    __syncthreads();
    buf ^= 1;
  }
#pragma unroll
  for (int mi = 0; mi < 4; ++mi) {
#pragma unroll
    for (int ni = 0; ni < 4; ++ni) {
      int col = colBlk + wn * 64 + ni * 16 + (l & 15);
      float bv = bias[col];
#pragma unroll
      for (int j = 0; j < 4; ++j) {
        int row = rowBlk + wm * 64 + mi * 16 + ((l >> 4) << 2) + j;
        C[(size_t)row * H + col] = acc[mi][ni][j] + bv + resid[(size_t)row * H + col];
      }
    }
  }
}

// ---------------- band dot products (bf16 gq,gk) ----------------
__global__ __launch_bounds__(256) void band_dots_kernel(
    const u16* __restrict__ gq, const u16* __restrict__ gk,
    float* __restrict__ znext, float* __restrict__ zprev) {
  __shared__ float buf[4];
  size_t idx = blockIdx.x;
  int i = (int)(idx & (S - 1));
  uint2 q2 = reinterpret_cast<const uint2*>(gq + idx * H)[threadIdx.x];
  float q0 = bf2f(q2.x & 0xffff), q1 = bf2f(q2.x >> 16);
  float q2f = bf2f(q2.y & 0xffff), q3 = bf2f(q2.y >> 16);
  float dn = 0.f, dp = 0.f;
  if (i < S - 1) {
    uint2 k2 = reinterpret_cast<const uint2*>(gk + (idx + 1) * H)[threadIdx.x];
    dn = q0 * bf2f(k2.x & 0xffff) + q1 * bf2f(k2.x >> 16) +
         q2f * bf2f(k2.y & 0xffff) + q3 * bf2f(k2.y >> 16);
  }
  if (i > 0) {
    uint2 k2 = reinterpret_cast<const uint2*>(gk + (idx - 1) * H)[threadIdx.x];
    dp = q0 * bf2f(k2.x & 0xffff) + q1 * bf2f(k2.x >> 16) +
         q2f * bf2f(k2.y & 0xffff) + q3 * bf2f(k2.y >> 16);
  }
  dn = block_sum256(dn, buf);
  dp = block_sum256(dp, buf);
  if (threadIdx.x == 0) { znext[idx] = dn; zprev[idx] = dp; }
}

// ---------------- band softmax + log prefix scan (honors attention_mask) ----
__global__ __launch_bounds__(1024) void band_prefix_kernel(
    const float* __restrict__ znext, const float* __restrict__ zprev,
    const int* __restrict__ am, const float* __restrict__ gp,
    float* __restrict__ sband, float* __restrict__ Cpre) {
  __shared__ float pd[S];
  __shared__ float scn[S];
  int b = blockIdx.x, i = threadIdx.x;
  size_t idx = (size_t)b * S + i;
  bool luv = (i < S - 1) && (am[((size_t)b * S + i) * S + i + 1] != 0);
  bool ldv = (i > 0) && (am[((size_t)b * S + i) * S + i - 1] != 0);
  float pf, pdn;
  if (!luv && !ldv) { pf = 0.f; pdn = 0.f; }
  else if (!ldv)    { pf = 1.f; pdn = 0.f; }
  else if (!luv)    { pf = 0.f; pdn = 1.f; }
  else {
    float lu = znext[idx] * (1.0f / (float)H);
    float ld = zprev[idx] * (1.0f / (float)H);
    float m = fmaxf(lu, ld);
    float eu = expf(lu - m), ed = expf(ld - m);
    float inv = 1.f / (eu + ed);
    pf = eu * inv; pdn = ed * inv;
  }
  pd[i] = pdn;
  __syncthreads();
  float sb = 0.f, L = 0.f;
  if (i < S - 1) {
    sb = sqrtf(pf * pd[i + 1] + 1e-9f);
    float gpv = gp[((size_t)b * S + i) * S + (i + 1)];
    float nm = gpv + (1.f - gpv) * sb;
    L = logf(nm + 1e-9f);
  }
  sband[idx] = sb;
  scn[i] = L;
  __syncthreads();
  for (int off = 1; off < S; off <<= 1) {
    float t = (i >= off) ? scn[i - off] : 0.f;
    __syncthreads();
    scn[i] += t;
    __syncthreads();
  }
  Cpre[idx] = (i > 0) ? scn[i - 1] : 0.f;
}

// ---------------- write g_attn and break_prob ----------------
__global__ __launch_bounds__(256) void gattn_write_kernel(
    const float* __restrict__ gp, const float* __restrict__ sband,
    const float* __restrict__ Cpre, float* __restrict__ ga, float* __restrict__ brk) {
  __shared__ float Crow[S];
  __shared__ float Srow[S];
  size_t bi = blockIdx.x;
  int b = (int)(bi >> 10), i = (int)(bi & (S - 1));
  reinterpret_cast<float4*>(Crow)[threadIdx.x] =
      reinterpret_cast<const float4*>(Cpre + (size_t)b * S)[threadIdx.x];
  reinterpret_cast<float4*>(Srow)[threadIdx.x] =
      reinterpret_cast<const float4*>(sband + (size_t)b * S)[threadIdx.x];
  __syncthreads();
  float Ci = Crow[i];
  size_t rowoff = bi * S;
  const float4 g4 = reinterpret_cast<const float4*>(gp + rowoff)[threadIdx.x];
  const float gparr[4] = {g4.x, g4.y, g4.z, g4.w};
  float go[4], bo_[4];
#pragma unroll
  for (int j = 0; j < 4; ++j) {
    int k = threadIdx.x * 4 + j;
    float gpv = gparr[j];
    float gav;
    if (k == i) {
      gav = gpv + (1.f - gpv) * SQ9;
    } else {
      float d = (k > i) ? (Crow[k] - Ci) : (Ci - Crow[k]);
      gav = expf(d) + 1e-9f;
    }
    float sval = (k == i + 1) ? Srow[i] : ((k == i - 1) ? Srow[k] : SQ9);
    go[j]  = gav;
    bo_[j] = gpv + (1.f - gpv) * sval;
  }
  reinterpret_cast<float4*>(ga + rowoff)[threadIdx.x]  = make_float4(go[0], go[1], go[2], go[3]);
  f32x4 bo4 = (f32x4){bo_[0], bo_[1], bo_[2], bo_[3]};
  __builtin_nontemporal_store(bo4, reinterpret_cast<f32x4*>(brk + rowoff) + threadIdx.x);
}

// ---------------- V transpose: v[B,S,H] bf16 -> vt[(b*NH+h)*64+d][S] ----------
__global__ __launch_bounds__(256) void transpose_v_kernel(
    const u16* __restrict__ v, u16* __restrict__ vt) {
  __shared__ __align__(16) u16 t[64][72];
  int sb = blockIdx.x, bh = blockIdx.y;
  int b = bh >> 4, h = bh & 15;
  int tid = threadIdx.x;
  int r = tid >> 3, c = (tid & 7) << 3;
#pragma unroll
  for (int p = 0; p < 2; ++p) {
    int row = p * 32 + r;
    uint4 d4 = *reinterpret_cast<const uint4*>(v + ((size_t)b * S + sb * 64 + row) * H + h * 64 + c);
    *reinterpret_cast<uint4*>(&t[row][c]) = d4;
  }
  __syncthreads();
  int d = tid >> 2, sq = (tid & 3) << 4;
  u32 w[8];
#pragma unroll
  for (int x = 0; x < 8; ++x)
    w[x] = (u32)t[sq + 2 * x][d] | ((u32)t[sq + 2 * x + 1][d] << 16);
  u16* dst = vt + ((size_t)bh * 64 + d) * S + sb * 64 + sq;
  reinterpret_cast<uint4*>(dst)[0] = make_uint4(w[0], w[1], w[2], w[3]);
  reinterpret_cast<uint4*>(dst)[1] = make_uint4(w[4], w[5], w[6], w[7]);
}

// ---------------- flash attention: scores + online softmax + PV -------------
// grid (S/64, B*NH), 4 waves; wave w owns q-rows qb*64 + w*16 .. +15 fully.
__global__ __launch_bounds__(256) void flash_kernel(
    const u16* __restrict__ q, const u16* __restrict__ k, const u16* __restrict__ vt,
    const u32* __restrict__ amb, const float* __restrict__ ga,
    float* __restrict__ scores, u16* __restrict__ ctx) {
  __shared__ __align__(16) u16 Qt[4096];
  __shared__ __align__(16) u16 Kt[2][4096];
  __shared__ __align__(16) u16 Vt[2][4096];
  __shared__ __align__(16) u16 Pt[4096];
  int qb = blockIdx.x, bh = blockIdx.y;
  int b = bh >> 4, h = bh & 15;
  int tid = threadIdx.x, wid = tid >> 6, l = tid & 63;
  int dr = l >> 3, sl = l & 7;
  int co = (sl ^ dr) << 3;
  const u16* qbase = q + ((size_t)b * S + qb * 64) * H + h * 64;
  const u16* kbase = k + (size_t)b * S * H + h * 64;
  const u16* vtb   = vt + (size_t)bh * 64 * S;
#pragma unroll
  for (int i = 0; i < 2; ++i) {
    int L = wid * 2 + i;
    gload16(qbase + (size_t)(L * 8 + dr) * H + co, &Qt[L * 512]);
    gload16(kbase + (size_t)(L * 8 + dr) * H + co, &Kt[0][L * 512]);
    gload16(vtb + (size_t)(L * 8 + dr) * S + co, &Vt[0][L * 512]);
  }
  __syncthreads();
  int sw = (l & 7) << 4;
  int qr = l & 15;
  bfrag qa[2];
#pragma unroll
  for (int ks = 0; ks < 2; ++ks) {
    int kb = (ks * 64 + ((l >> 4) << 4)) ^ sw;
    qa[ks] = *(const bfrag*)((const char*)Qt + (wid * 16 + qr) * 128 + kb);
  }
  float m_run[4], l_run[4];
  f32x4 oacc[4];
#pragma unroll
  for (int j = 0; j < 4; ++j) { m_run[j] = NEG_INF; l_run[j] = 0.f; }
#pragma unroll
  for (int nb = 0; nb < 4; ++nb) oacc[nb] = (f32x4){0.f, 0.f, 0.f, 0.f};
  int buf = 0;
  int rowg0 = qb * 64 + wid * 16 + ((l >> 4) << 2);
  for (int kt = 0; kt < 16; ++kt) {
    if (kt < 15) {
      const u16* kb2 = kbase + (size_t)((kt + 1) * 64) * H;
#pragma unroll
      for (int i = 0; i < 2; ++i) {
        int L = wid * 2 + i;
        gload16(kb2 + (size_t)(L * 8 + dr) * H + co, &Kt[buf ^ 1][L * 512]);
        gload16(vtb + (size_t)(L * 8 + dr) * S + (kt + 1) * 64 + co, &Vt[buf ^ 1][L * 512]);
      }
    }
    // ---- QK^T ----
    f32x4 acc[4];
#pragma unroll
    for (int nb = 0; nb < 4; ++nb) acc[nb] = (f32x4){0.f, 0.f, 0.f, 0.f};
#pragma unroll
    for (int ks = 0; ks < 2; ++ks) {
      int kb = (ks * 64 + ((l >> 4) << 4)) ^ sw;
#pragma unroll
      for (int nb = 0; nb < 4; ++nb) {
        bfrag bv = *(const bfrag*)((const char*)Kt[buf] + (nb * 16 + qr) * 128 + kb);
        acc[nb] = __builtin_amdgcn_mfma_f32_16x16x32_bf16(qa[ks], bv, acc[nb], 0, 0, 0);
      }
    }
    // ---- mask + scores write + tile max ----
    float vals[4][4];
    float tm[4] = {NEG_INF, NEG_INF, NEG_INF, NEG_INF};
#pragma unroll
    for (int j = 0; j < 4; ++j) {
      int row = rowg0 + j;
      const u32* amw = amb + ((size_t)b * S + row) * 32 + kt * 2;
      u32 w0 = amw[0], w1 = amw[1];
      float* srow = scores + ((size_t)bh * S + row) * S + kt * 64;
#pragma unroll
      for (int nb = 0; nb < 4; ++nb) {
        int col = nb * 16 + qr;
        int colg = kt * 64 + col;
        u32 word = (nb < 2) ? w0 : w1;
        int keep = (int)((word >> (col & 31)) & 1u) | (row == colg);
        float v = keep ? acc[nb][j] * 0.125f : NEG_INF;
        vals[nb][j] = v;
        __builtin_nontemporal_store(v, srow + col);
        tm[j] = fmaxf(tm[j], v);
      }
    }
#pragma unroll
    for (int j = 0; j < 4; ++j) {
#pragma unroll
      for (int o = 1; o < 16; o <<= 1) tm[j] = fmaxf(tm[j], __shfl_xor(tm[j], o));
    }
    // ---- online softmax update + P write + O rescale ----
#pragma unroll
    for (int j = 0; j < 4; ++j) {
      int row = rowg0 + j;
      int prow = wid * 16 + ((l >> 4) << 2) + j;
      char* ptrow = (char*)Pt + prow * 128;
      int psw = (prow & 7) << 4;
      const float* garow = ga + ((size_t)b * S + row) * S + kt * 64;
      float mn = fmaxf(m_run[j], tm[j]);
      float p[4];
      float sc = 1.f, lsum = 0.f;
      if (mn > NEG_INF) {
        sc = expf(m_run[j] - mn);
#pragma unroll
        for (int nb = 0; nb < 4; ++nb) p[nb] = expf(vals[nb][j] - mn);
        lsum = p[0] + p[1] + p[2] + p[3];
      } else {
#pragma unroll
        for (int nb = 0; nb < 4; ++nb) p[nb] = 0.f;
      }
#pragma unroll
      for (int o = 1; o < 16; o <<= 1) lsum += __shfl_xor(lsum, o);
      m_run[j] = mn;
      l_run[j] = l_run[j] * sc + lsum;
#pragma unroll
      for (int nb = 0; nb < 4; ++nb) {
        float pg = p[nb] * garow[nb * 16 + qr];
        *(u16*)(ptrow + (((nb * 16 + qr) * 2) ^ psw)) = f2bf(pg);
        oacc[nb][j] *= sc;
      }
    }
    // ---- PV (per-wave P rows; lanes only read their own wave's 16 rows) ----
#pragma unroll
    for (int ks = 0; ks < 2; ++ks) {
      int kb = (ks * 64 + ((l >> 4) << 4)) ^ sw;
      bfrag pa = *(const bfrag*)((const char*)Pt + (wid * 16 + qr) * 128 + kb);
#pragma unroll
      for (int nb = 0; nb < 4; ++nb) {
        bfrag vv = *(const bfrag*)((const char*)Vt[buf] + (nb * 16 + qr) * 128 + kb);
        oacc[nb] = __builtin_amdgcn_mfma_f32_16x16x32_bf16(pa, vv, oacc[nb], 0, 0, 0);
      }
    }
    __syncthreads();
    buf ^= 1;
  }
  // ---- epilogue: ctx = O / l ----
#pragma unroll
  for (int j = 0; j < 4; ++j) {
    int row = rowg0 + j;
    float ir = 1.f / l_run[j];
#pragma unroll
    for (int nb = 0; nb < 4; ++nb) {
      int d = nb * 16 + qr;
      ctx[((size_t)b * S + row) * H + h * 64 + d] = f2bf(oacc[nb][j] * ir);
    }
  }
}

// ---------------- launch ----------------
extern "C" void kernel_launch(void* const* d_in, const int* in_sizes, int n_in,
                              void* d_out, int out_size, void* d_ws, size_t ws_size,
                              hipStream_t stream) {
  const float* hidden = (const float*)d_in[0];
  const float* gp     = (const float*)d_in[1];
  const int*   am     = (const int*)d_in[2];
  const float* Wq = (const float*)d_in[3];  const float* bq = (const float*)d_in[4];
  const float* Wk = (const float*)d_in[5];  const float* bk = (const float*)d_in[6];
  const float* Wv = (const float*)d_in[7];  const float* bv = (const float*)d_in[8];
  const float* gWq = (const float*)d_in[9]; const float* gbq = (const float*)d_in[10];
  const float* gWk = (const float*)d_in[11];const float* gbk = (const float*)d_in[12];
  const float* glns = (const float*)d_in[13]; const float* glnb = (const float*)d_in[14];
  const float* Wo = (const float*)d_in[15]; const float* bo = (const float*)d_in[16];
  const float* olns = (const float*)d_in[17]; const float* olnb = (const float*)d_in[18];

  float* out    = (float*)d_out;
  float* scores = out + (size_t)BB * S * H;
  float* gattn  = scores + (size_t)BB * NHD * S * S;
  float* brk    = gattn + (size_t)BB * S * S;

  const size_t MB = 1u << 20;
  char* w = (char*)d_ws;
  u16* Wqkvbf = (u16*)(w);            // 6 MB  [Wq|Wk|Wv] rows
  u16* gWbf   = (u16*)(w + 6 * MB);   // 4 MB  [gWq|gWk]
  u16* Wobf   = (u16*)(w + 10 * MB);  // 2 MB
  u16* hbf    = (u16*)(w + 12 * MB);  // 8 MB ; reused for ctx after QKV GEMM
  u16* ctxbf  = hbf;
  u16* hsbf   = (u16*)(w + 20 * MB);  // 8 MB ; reused for v after gq/gk
  u16* vbf    = hsbf;
  u16* gqbf   = (u16*)(w + 28 * MB);  // 8 MB ; reused for q
  u16* qbf    = gqbf;
  u16* gkbf   = (u16*)(w + 36 * MB);  // 8 MB ; reused for k
  u16* kbf    = gkbf;
  u16* vtb    = (u16*)(w + 44 * MB);  // 8 MB
  float* densef = (float*)(w + 20 * MB);  // 16.8 MB (v/q/k slots, free post-flash)
  u32* amb    = (u32*)(w + 52 * MB);  // 512 KB
  float* znext  = (float*)(w + 53 * MB);
  float* zprev  = znext + BB * S;
  float* sbandA = zprev + BB * S;
  float* CpreA  = sbandA + BB * S;

  dim3 blk(256);
  dim3 agrid(S / 64, BB * NHD);

  cast_all_kernel<<<(6 * 262144 + 1048576) / 256, blk, 0, stream>>>(
      Wq, Wk, Wv, gWq, gWk, Wo, hidden, Wqkvbf);
  pack_mask_kernel<<<(BB * S * S) / 256, blk, 0, stream>>>(am, amb);

  // ---- group attention path ----
  ln_kernel<u16><<<BB * S, blk, 0, stream>>>(hidden, glns, glnb, hsbf);
  gemm_bt3<<<dim3(16, 32), blk, 0, stream>>>(hsbf, gWbf, gbq, gbk, nullptr,
                                             gqbf, gkbf, nullptr);
  band_dots_kernel<<<BB * S, blk, 0, stream>>>(gqbf, gkbf, znext, zprev);
  band_prefix_kernel<<<BB, 1024, 0, stream>>>(znext, zprev, am, gp, sbandA, CpreA);
  gattn_write_kernel<<<BB * S, blk, 0, stream>>>(gp, sbandA, CpreA, gattn, brk);

  // ---- main attention ----
  gemm_bt3<<<dim3(24, 32), blk, 0, stream>>>(hbf, Wqkvbf, bq, bk, bv,
                                             qbf, kbf, vbf);
  transpose_v_kernel<<<agrid, blk, 0, stream>>>(vbf, vtb);
  flash_kernel<<<agrid, blk, 0, stream>>>(qbf, kbf, vtb, amb, gattn, scores, ctxbf);

  // ---- output projection + residual + LN ----
  gemm_dense<<<dim3(8, 32), blk, 0, stream>>>(ctxbf, Wobf, bo, hidden, densef);
  ln_kernel<float><<<BB * S, blk, 0, stream>>>(densef, olns, olnb, out);
}

// Round 5
// 269.595 us; speedup vs baseline: 5.6176x; 1.0243x over previous
//
#include <hip/hip_runtime.h>
#include <math.h>

#define BB 4
#define S 1024
#define H 1024
#define NHD 16
#define DH 64
#define LN_EPS 1e-12f
#define SQ9 3.1622776601683795e-5f
#define NEG_INF (-__builtin_inff())

typedef unsigned short u16;
typedef unsigned int u32;
using bfrag = __attribute__((ext_vector_type(8))) short;   // 8 bf16 (MFMA A/B frag)
using f32x4 = __attribute__((ext_vector_type(4))) float;   // MFMA C/D frag

typedef __attribute__((address_space(1))) void void_g;
typedef __attribute__((address_space(3))) void void_l;

__device__ __forceinline__ void gload16(const void* g, void* l) {
  __builtin_amdgcn_global_load_lds((void_g*)g, (void_l*)l, 16, 0, 0);
}

__device__ __forceinline__ u16 f2bf(float f) {
  u32 u = __builtin_bit_cast(u32, f);
  u32 r = (u + 0x7fffu + ((u >> 16) & 1u)) >> 16;
  return (u16)r;
}
__device__ __forceinline__ float bf2f(u32 b) {
  u32 u = b << 16;
  return __builtin_bit_cast(float, u);
}

__device__ __forceinline__ float block_sum256(float v, float* buf) {
#pragma unroll
  for (int o = 32; o > 0; o >>= 1) v += __shfl_down(v, o);
  if ((threadIdx.x & 63) == 0) buf[threadIdx.x >> 6] = v;
  __syncthreads();
  float r = buf[0] + buf[1] + buf[2] + buf[3];
  __syncthreads();
  return r;
}

// ---------------- prep: cast 5 weights + hidden, pack mask, group-LN -------
// blocks [0,9216): cast [Wq|Wk|Wv|gWq|gWk|hidden] -> dstW (contiguous bf16)
// blocks [9216,25600): pack am bits -> amb
// blocks [25600,29696): LayerNorm(hidden; g_ln) -> hsbf (bf16)
__global__ __launch_bounds__(256) void prep_kernel(
    const float* __restrict__ Wq, const float* __restrict__ Wk, const float* __restrict__ Wv,
    const float* __restrict__ gWq, const float* __restrict__ gWk,
    const float* __restrict__ hidden, const int* __restrict__ am,
    const float* __restrict__ glns, const float* __restrict__ glnb,
    u16* __restrict__ dstW, u32* __restrict__ amb, u16* __restrict__ hsbf) {
  __shared__ float buf[4];
  int bid = blockIdx.x;
  if (bid < 9216) {
    const int WQ = 262144;
    int i = bid * 256 + threadIdx.x;
    const float* src; int off;
    if      (i < 1 * WQ) { src = Wq;  off = 0; }
    else if (i < 2 * WQ) { src = Wk;  off = 1 * WQ; }
    else if (i < 3 * WQ) { src = Wv;  off = 2 * WQ; }
    else if (i < 4 * WQ) { src = gWq; off = 3 * WQ; }
    else if (i < 5 * WQ) { src = gWk; off = 4 * WQ; }
    else                 { src = hidden; off = 5 * WQ; }
    float4 v = reinterpret_cast<const float4*>(src)[i - off];
    u32 lo = (u32)f2bf(v.x) | ((u32)f2bf(v.y) << 16);
    u32 hi = (u32)f2bf(v.z) | ((u32)f2bf(v.w) << 16);
    reinterpret_cast<uint2*>(dstW)[i] = make_uint2(lo, hi);
  } else if (bid < 25600) {
    size_t t = (size_t)(bid - 9216) * 256 + threadIdx.x;
    int v = am[t] != 0;
    unsigned long long m = __ballot(v);
    int lane = threadIdx.x & 63;
    if (lane == 0)       amb[t >> 5] = (u32)m;
    else if (lane == 32) amb[t >> 5] = (u32)(m >> 32);
  } else {
    size_t row = bid - 25600;
    const float4 xv = reinterpret_cast<const float4*>(hidden + row * H)[threadIdx.x];
    float s  = xv.x + xv.y + xv.z + xv.w;
    float s2 = xv.x * xv.x + xv.y * xv.y + xv.z * xv.z + xv.w * xv.w;
    s  = block_sum256(s, buf);
    s2 = block_sum256(s2, buf);
    float mu  = s * (1.0f / H);
    float var = s2 * (1.0f / H) - mu * mu;
    float inv = rsqrtf(var + LN_EPS);
    const float4 sv = reinterpret_cast<const float4*>(glns)[threadIdx.x];
    const float4 bv = reinterpret_cast<const float4*>(glnb)[threadIdx.x];
    float o0 = (xv.x - mu) * inv * sv.x + bv.x;
    float o1 = (xv.y - mu) * inv * sv.y + bv.y;
    float o2 = (xv.z - mu) * inv * sv.z + bv.z;
    float o3 = (xv.w - mu) * inv * sv.w + bv.w;
    u32 lo = (u32)f2bf(o0) | ((u32)f2bf(o1) << 16);
    u32 hi = (u32)f2bf(o2) | ((u32)f2bf(o3) << 16);
    reinterpret_cast<uint2*>(hsbf + row * H)[threadIdx.x] = make_uint2(lo, hi);
  }
}

// ---------------- Wo cast (runs after mega-GEMM into freed hsbf slot) -------
__global__ __launch_bounds__(256) void cast_wo_kernel(const float* __restrict__ Wo,
                                                      u16* __restrict__ dst) {
  int i = blockIdx.x * 256 + threadIdx.x;
  float4 v = reinterpret_cast<const float4*>(Wo)[i];
  u32 lo = (u32)f2bf(v.x) | ((u32)f2bf(v.y) << 16);
  u32 hi = (u32)f2bf(v.z) | ((u32)f2bf(v.w) << 16);
  reinterpret_cast<uint2*>(dst)[i] = make_uint2(lo, hi);
}

// ---------------- mega-GEMM: 5 projections in one launch --------------------
// Wcat [5120][1024] = [Wq|Wk|Wv|gWq|gWk] rows. which = lx>>3 selects slab:
// 0:q(A=hbf) 1:k(A=hbf) 2:v(A=hbf, output TRANSPOSED to vt) 3:gq(A=hsbf) 4:gk(A=hsbf)
// 128x128 tile, BK=64, 2-phase double-buffered, XOR-swizzled LDS, XCD swizzle.
__global__ __launch_bounds__(256) void mega_gemm(
    const u16* __restrict__ hbf, const u16* __restrict__ hsbf,
    const u16* __restrict__ Wcat,
    const float* __restrict__ bq, const float* __restrict__ bk, const float* __restrict__ bv,
    const float* __restrict__ gbq, const float* __restrict__ gbk,
    u16* __restrict__ q, u16* __restrict__ k, u16* __restrict__ vt,
    u16* __restrict__ gq, u16* __restrict__ gk) {
  __shared__ __align__(16) u16 SM[32768];  // [A0|A1|B0|B1] 8192 u16 each
  const int Kdim = H;
  int fid = blockIdx.x + blockIdx.y * 40;          // nwg = 1280
  int swz = (fid & 7) * 160 + (fid >> 3);          // bijective XCD swizzle
  int lx = swz % 40, ly = swz / 40;
  int which = lx >> 3;
  const u16* A = (which < 3) ? hbf : hsbf;
  int rowBlk = ly * 128, colBlk = lx * 128;
  int tid = threadIdx.x, wid = tid >> 6, l = tid & 63;
  int dr = l >> 3, sl = l & 7;
  int co = (sl ^ dr) << 3;
  const u16* Ag = A + (size_t)rowBlk * Kdim;
  const u16* Bg = Wcat + (size_t)colBlk * Kdim;
  f32x4 acc[4][4];
#pragma unroll
  for (int i = 0; i < 4; ++i)
#pragma unroll
    for (int j = 0; j < 4; ++j) acc[i][j] = (f32x4){0.f, 0.f, 0.f, 0.f};
#pragma unroll
  for (int i = 0; i < 4; ++i) {
    int L = wid * 4 + i;
    gload16(Ag + (size_t)(L * 8 + dr) * Kdim + co, &SM[L * 512]);
    gload16(Bg + (size_t)(L * 8 + dr) * Kdim + co, &SM[16384 + L * 512]);
  }
  __syncthreads();
  int wm = wid >> 1, wn = wid & 1;
  const int nt = Kdim >> 6;
  int buf = 0;
  int sw = (l & 7) << 4;
  for (int t = 0; t < nt; ++t) {
    if (t + 1 < nt) {
      int k0 = (t + 1) << 6;
      int dstoff = (buf ^ 1) * 8192;
#pragma unroll
      for (int i = 0; i < 4; ++i) {
        int L = wid * 4 + i;
        gload16(Ag + (size_t)(L * 8 + dr) * Kdim + k0 + co, &SM[dstoff + L * 512]);
        gload16(Bg + (size_t)(L * 8 + dr) * Kdim + k0 + co, &SM[16384 + dstoff + L * 512]);
      }
    }
    const char* Ab = (const char*)&SM[buf * 8192];
    const char* Bb = (const char*)&SM[16384 + buf * 8192];
#pragma unroll
    for (int ks = 0; ks < 2; ++ks) {
      int kb = (ks * 64 + ((l >> 4) << 4)) ^ sw;
      bfrag af[4], bfv[4];
#pragma unroll
      for (int mi = 0; mi < 4; ++mi)
        af[mi] = *(const bfrag*)(Ab + (wm * 64 + mi * 16 + (l & 15)) * 128 + kb);
#pragma unroll
      for (int ni = 0; ni < 4; ++ni)
        bfv[ni] = *(const bfrag*)(Bb + (wn * 64 + ni * 16 + (l & 15)) * 128 + kb);
#pragma unroll
      for (int mi = 0; mi < 4; ++mi)
#pragma unroll
        for (int ni = 0; ni < 4; ++ni)
          acc[mi][ni] = __builtin_amdgcn_mfma_f32_16x16x32_bf16(af[mi], bfv[ni], acc[mi][ni], 0, 0, 0);
    }
    __syncthreads();
    buf ^= 1;
  }
  const float* bias = (which == 0) ? bq : (which == 1) ? bk : (which == 2) ? bv
                      : (which == 3) ? gbq : gbk;
  if (which == 2) {
    // transpose via LDS restage: T[col][tok], stride 144 u16 (288B, 16B-aligned)
    u16* T = SM;
#pragma unroll
    for (int mi = 0; mi < 4; ++mi) {
#pragma unroll
      for (int ni = 0; ni < 4; ++ni) {
        int c = wn * 64 + ni * 16 + (l & 15);
        float bvv = bias[(colBlk & 1023) + c];
        int tokb = wm * 64 + mi * 16 + ((l >> 4) << 2);
        u32 w0 = (u32)f2bf(acc[mi][ni][0] + bvv) | ((u32)f2bf(acc[mi][ni][1] + bvv) << 16);
        u32 w1 = (u32)f2bf(acc[mi][ni][2] + bvv) | ((u32)f2bf(acc[mi][ni][3] + bvv) << 16);
        *(u32*)&T[c * 144 + tokb]     = w0;
        *(u32*)&T[c * 144 + tokb + 2] = w1;
      }
    }
    __syncthreads();
    int col = tid >> 1, th = tid & 1;
    int g = (colBlk & 1023) + col;
    int bb = rowBlk >> 10;
    int s0 = (rowBlk & 1023) + th * 64;
    const uint4* src = (const uint4*)&T[col * 144 + th * 64];
    u16* dst = vt + ((size_t)(bb * 1024 + g)) * S + s0;
#pragma unroll
    for (int i = 0; i < 8; ++i) reinterpret_cast<uint4*>(dst)[i] = src[i];
  } else {
    u16* O = (which == 0) ? q : (which == 1) ? k : (which == 3) ? gq : gk;
#pragma unroll
    for (int mi = 0; mi < 4; ++mi) {
#pragma unroll
      for (int ni = 0; ni < 4; ++ni) {
        int col = (colBlk + wn * 64 + ni * 16 + (l & 15)) & 1023;
        float bvv = bias[col];
#pragma unroll
        for (int j = 0; j < 4; ++j) {
          int row = rowBlk + wm * 64 + mi * 16 + ((l >> 4) << 2) + j;
          O[(size_t)row * H + col] = f2bf(acc[mi][ni][j] + bvv);
        }
      }
    }
  }
}

// ---------------- dense: C = A @ Wo^T + bo + hidden (bf16 out) --------------
__global__ __launch_bounds__(256) void gemm_dense(
    const u16* __restrict__ A, const u16* __restrict__ Bw,
    const float* __restrict__ bias, const float* __restrict__ resid,
    u16* __restrict__ C) {
  __shared__ __align__(16) u16 SM[32768];
  const int Kdim = H;
  int fid = blockIdx.x + blockIdx.y * 8;           // nwg = 256
  int swz = (fid & 7) * 32 + (fid >> 3);
  int lx = swz & 7, ly = swz >> 3;
  int rowBlk = ly * 128, colBlk = lx * 128;
  int tid = threadIdx.x, wid = tid >> 6, l = tid & 63;
  int dr = l >> 3, sl = l & 7;
  int co = (sl ^ dr) << 3;
  const u16* Ag = A + (size_t)rowBlk * Kdim;
  const u16* Bg = Bw + (size_t)colBlk * Kdim;
  f32x4 acc[4][4];
#pragma unroll
  for (int i = 0; i < 4; ++i)
#pragma unroll
    for (int j = 0; j < 4; ++j) acc[i][j] = (f32x4){0.f, 0.f, 0.f, 0.f};
#pragma unroll
  for (int i = 0; i < 4; ++i) {
    int L = wid * 4 + i;
    gload16(Ag + (size_t)(L * 8 + dr) * Kdim + co, &SM[L * 512]);
    gload16(Bg + (size_t)(L * 8 + dr) * Kdim + co, &SM[16384 + L * 512]);
  }
  __syncthreads();
  int wm = wid >> 1, wn = wid & 1;
  const int nt = Kdim >> 6;
  int buf = 0;
  int sw = (l & 7) << 4;
  for (int t = 0; t < nt; ++t) {
    if (t + 1 < nt) {
      int k0 = (t + 1) << 6;
      int dstoff = (buf ^ 1) * 8192;
#pragma unroll
      for (int i = 0; i < 4; ++i) {
        int L = wid * 4 + i;
        gload16(Ag + (size_t)(L * 8 + dr) * Kdim + k0 + co, &SM[dstoff + L * 512]);
        gload16(Bg + (size_t)(L * 8 + dr) * Kdim + k0 + co, &SM[16384 + dstoff + L * 512]);
      }
    }
    const char* Ab = (const char*)&SM[buf * 8192];
    const char* Bb = (const char*)&SM[16384 + buf * 8192];
#pragma unroll
    for (int ks = 0; ks < 2; ++ks) {
      int kb = (ks * 64 + ((l >> 4) << 4)) ^ sw;
      bfrag af[4], bfv[4];
#pragma unroll
      for (int mi = 0; mi < 4; ++mi)
        af[mi] = *(const bfrag*)(Ab + (wm * 64 + mi * 16 + (l & 15)) * 128 + kb);
#pragma unroll
      for (int ni = 0; ni < 4; ++ni)
        bfv[ni] = *(const bfrag*)(Bb + (wn * 64 + ni * 16 + (l & 15)) * 128 + kb);
#pragma unroll
      for (int mi = 0; mi < 4; ++mi)
#pragma unroll
        for (int ni = 0; ni < 4; ++ni)
          acc[mi][ni] = __builtin_amdgcn_mfma_f32_16x16x32_bf16(af[mi], bfv[ni], acc[mi][ni], 0, 0, 0);
    }
    __syncthreads();
    buf ^= 1;
  }
#pragma unroll
  for (int mi = 0; mi < 4; ++mi) {
#pragma unroll
    for (int ni = 0; ni < 4; ++ni) {
      int col = colBlk + wn * 64 + ni * 16 + (l & 15);
      float bvv = bias[col];
#pragma unroll
      for (int j = 0; j < 4; ++j) {
        int row = rowBlk + wm * 64 + mi * 16 + ((l >> 4) << 2) + j;
        C[(size_t)row * H + col] = f2bf(acc[mi][ni][j] + bvv + resid[(size_t)row * H + col]);
      }
    }
  }
}

// ---------------- band dot products (bf16 gq,gk) ----------------
__global__ __launch_bounds__(256) void band_dots_kernel(
    const u16* __restrict__ gq, const u16* __restrict__ gk,
    float* __restrict__ znext, float* __restrict__ zprev) {
  __shared__ float buf[4];
  size_t idx = blockIdx.x;
  int i = (int)(idx & (S - 1));
  uint2 q2 = reinterpret_cast<const uint2*>(gq + idx * H)[threadIdx.x];
  float q0 = bf2f(q2.x & 0xffff), q1 = bf2f(q2.x >> 16);
  float q2f = bf2f(q2.y & 0xffff), q3 = bf2f(q2.y >> 16);
  float dn = 0.f, dp = 0.f;
  if (i < S - 1) {
    uint2 k2 = reinterpret_cast<const uint2*>(gk + (idx + 1) * H)[threadIdx.x];
    dn = q0 * bf2f(k2.x & 0xffff) + q1 * bf2f(k2.x >> 16) +
         q2f * bf2f(k2.y & 0xffff) + q3 * bf2f(k2.y >> 16);
  }
  if (i > 0) {
    uint2 k2 = reinterpret_cast<const uint2*>(gk + (idx - 1) * H)[threadIdx.x];
    dp = q0 * bf2f(k2.x & 0xffff) + q1 * bf2f(k2.x >> 16) +
         q2f * bf2f(k2.y & 0xffff) + q3 * bf2f(k2.y >> 16);
  }
  dn = block_sum256(dn, buf);
  dp = block_sum256(dp, buf);
  if (threadIdx.x == 0) { znext[idx] = dn; zprev[idx] = dp; }
}

// ---------------- band softmax + log prefix scan ----------------
__global__ __launch_bounds__(1024) void band_prefix_kernel(
    const float* __restrict__ znext, const float* __restrict__ zprev,
    const int* __restrict__ am, const float* __restrict__ gp,
    float* __restrict__ sband, float* __restrict__ Cpre) {
  __shared__ float pd[S];
  __shared__ float scn[S];
  int b = blockIdx.x, i = threadIdx.x;
  size_t idx = (size_t)b * S + i;
  bool luv = (i < S - 1) && (am[((size_t)b * S + i) * S + i + 1] != 0);
  bool ldv = (i > 0) && (am[((size_t)b * S + i) * S + i - 1] != 0);
  float pf, pdn;
  if (!luv && !ldv) { pf = 0.f; pdn = 0.f; }
  else if (!ldv)    { pf = 1.f; pdn = 0.f; }
  else if (!luv)    { pf = 0.f; pdn = 1.f; }
  else {
    float lu = znext[idx] * (1.0f / (float)H);
    float ld = zprev[idx] * (1.0f / (float)H);
    float m = fmaxf(lu, ld);
    float eu = expf(lu - m), ed = expf(ld - m);
    float inv = 1.f / (eu + ed);
    pf = eu * inv; pdn = ed * inv;
  }
  pd[i] = pdn;
  __syncthreads();
  float sb = 0.f, L = 0.f;
  if (i < S - 1) {
    sb = sqrtf(pf * pd[i + 1] + 1e-9f);
    float gpv = gp[((size_t)b * S + i) * S + (i + 1)];
    float nm = gpv + (1.f - gpv) * sb;
    L = logf(nm + 1e-9f);
  }
  sband[idx] = sb;
  scn[i] = L;
  __syncthreads();
  for (int off = 1; off < S; off <<= 1) {
    float t = (i >= off) ? scn[i - off] : 0.f;
    __syncthreads();
    scn[i] += t;
    __syncthreads();
  }
  Cpre[idx] = (i > 0) ? scn[i - 1] : 0.f;
}

// ---------------- write g_attn and break_prob ----------------
__global__ __launch_bounds__(256) void gattn_write_kernel(
    const float* __restrict__ gp, const float* __restrict__ sband,
    const float* __restrict__ Cpre, float* __restrict__ ga, float* __restrict__ brk) {
  __shared__ float Crow[S];
  __shared__ float Srow[S];
  size_t bi = blockIdx.x;
  int b = (int)(bi >> 10), i = (int)(bi & (S - 1));
  reinterpret_cast<float4*>(Crow)[threadIdx.x] =
      reinterpret_cast<const float4*>(Cpre + (size_t)b * S)[threadIdx.x];
  reinterpret_cast<float4*>(Srow)[threadIdx.x] =
      reinterpret_cast<const float4*>(sband + (size_t)b * S)[threadIdx.x];
  __syncthreads();
  float Ci = Crow[i];
  size_t rowoff = bi * S;
  const float4 g4 = reinterpret_cast<const float4*>(gp + rowoff)[threadIdx.x];
  const float gparr[4] = {g4.x, g4.y, g4.z, g4.w};
  float go[4], bo_[4];
#pragma unroll
  for (int j = 0; j < 4; ++j) {
    int k = threadIdx.x * 4 + j;
    float gpv = gparr[j];
    float gav;
    if (k == i) {
      gav = gpv + (1.f - gpv) * SQ9;
    } else {
      float d = (k > i) ? (Crow[k] - Ci) : (Ci - Crow[k]);
      gav = expf(d) + 1e-9f;
    }
    float sval = (k == i + 1) ? Srow[i] : ((k == i - 1) ? Srow[k] : SQ9);
    go[j]  = gav;
    bo_[j] = gpv + (1.f - gpv) * sval;
  }
  reinterpret_cast<float4*>(ga + rowoff)[threadIdx.x]  = make_float4(go[0], go[1], go[2], go[3]);
  f32x4 bo4 = (f32x4){bo_[0], bo_[1], bo_[2], bo_[3]};
  __builtin_nontemporal_store(bo4, reinterpret_cast<f32x4*>(brk + rowoff) + threadIdx.x);
}

// ---------------- flash attention: scores + online softmax + PV -------------
__global__ __launch_bounds__(256) void flash_kernel(
    const u16* __restrict__ q, const u16* __restrict__ k, const u16* __restrict__ vt,
    const u32* __restrict__ amb, const float* __restrict__ ga,
    float* __restrict__ scores, u16* __restrict__ ctx) {
  __shared__ __align__(16) u16 Qt[4096];
  __shared__ __align__(16) u16 Kt[2][4096];
  __shared__ __align__(16) u16 Vt[2][4096];
  __shared__ __align__(16) u16 Pt[4096];
  int fid = blockIdx.x + blockIdx.y * 16;          // nwg = 1024
  int swz = (fid & 7) * 128 + (fid >> 3);
  int qb = swz & 15, bh = swz >> 4;
  int b = bh >> 4, h = bh & 15;
  int tid = threadIdx.x, wid = tid >> 6, l = tid & 63;
  int dr = l >> 3, sl = l & 7;
  int co = (sl ^ dr) << 3;
  const u16* qbase = q + ((size_t)b * S + qb * 64) * H + h * 64;
  const u16* kbase = k + (size_t)b * S * H + h * 64;
  const u16* vtb   = vt + (size_t)bh * 64 * S;
#pragma unroll
  for (int i = 0; i < 2; ++i) {
    int L = wid * 2 + i;
    gload16(qbase + (size_t)(L * 8 + dr) * H + co, &Qt[L * 512]);
    gload16(kbase + (size_t)(L * 8 + dr) * H + co, &Kt[0][L * 512]);
    gload16(vtb + (size_t)(L * 8 + dr) * S + co, &Vt[0][L * 512]);
  }
  __syncthreads();
  int sw = (l & 7) << 4;
  int qr = l & 15;
  bfrag qa[2];
#pragma unroll
  for (int ks = 0; ks < 2; ++ks) {
    int kb = (ks * 64 + ((l >> 4) << 4)) ^ sw;
    qa[ks] = *(const bfrag*)((const char*)Qt + (wid * 16 + qr) * 128 + kb);
  }
  float m_run[4], l_run[4];
  f32x4 oacc[4];
#pragma unroll
  for (int j = 0; j < 4; ++j) { m_run[j] = NEG_INF; l_run[j] = 0.f; }
#pragma unroll
  for (int nb = 0; nb < 4; ++nb) oacc[nb] = (f32x4){0.f, 0.f, 0.f, 0.f};
  int buf = 0;
  int rowg0 = qb * 64 + wid * 16 + ((l >> 4) << 2);
  for (int kt = 0; kt < 16; ++kt) {
    if (kt < 15) {
      const u16* kb2 = kbase + (size_t)((kt + 1) * 64) * H;
#pragma unroll
      for (int i = 0; i < 2; ++i) {
        int L = wid * 2 + i;
        gload16(kb2 + (size_t)(L * 8 + dr) * H + co, &Kt[buf ^ 1][L * 512]);
        gload16(vtb + (size_t)(L * 8 + dr) * S + (kt + 1) * 64 + co, &Vt[buf ^ 1][L * 512]);
      }
    }
    f32x4 acc[4];
#pragma unroll
    for (int nb = 0; nb < 4; ++nb) acc[nb] = (f32x4){0.f, 0.f, 0.f, 0.f};
#pragma unroll
    for (int ks = 0; ks < 2; ++ks) {
      int kb = (ks * 64 + ((l >> 4) << 4)) ^ sw;
#pragma unroll
      for (int nb = 0; nb < 4; ++nb) {
        bfrag bv = *(const bfrag*)((const char*)Kt[buf] + (nb * 16 + qr) * 128 + kb);
        acc[nb] = __builtin_amdgcn_mfma_f32_16x16x32_bf16(qa[ks], bv, acc[nb], 0, 0, 0);
      }
    }
    float vals[4][4];
    float tm[4] = {NEG_INF, NEG_INF, NEG_INF, NEG_INF};
#pragma unroll
    for (int j = 0; j < 4; ++j) {
      int row = rowg0 + j;
      const u32* amw = amb + ((size_t)b * S + row) * 32 + kt * 2;
      u32 w0 = amw[0], w1 = amw[1];
      float* srow = scores + ((size_t)bh * S + row) * S + kt * 64;
#pragma unroll
      for (int nb = 0; nb < 4; ++nb) {
        int col = nb * 16 + qr;
        int colg = kt * 64 + col;
        u32 word = (nb < 2) ? w0 : w1;
        int keep = (int)((word >> (col & 31)) & 1u) | (row == colg);
        float v = keep ? acc[nb][j] * 0.125f : NEG_INF;
        vals[nb][j] = v;
        __builtin_nontemporal_store(v, srow + col);
        tm[j] = fmaxf(tm[j], v);
      }
    }
#pragma unroll
    for (int j = 0; j < 4; ++j) {
#pragma unroll
      for (int o = 1; o < 16; o <<= 1) tm[j] = fmaxf(tm[j], __shfl_xor(tm[j], o));
    }
#pragma unroll
    for (int j = 0; j < 4; ++j) {
      int row = rowg0 + j;
      int prow = wid * 16 + ((l >> 4) << 2) + j;
      char* ptrow = (char*)Pt + prow * 128;
      int psw = (prow & 7) << 4;
      const float* garow = ga + ((size_t)b * S + row) * S + kt * 64;
      float mn = fmaxf(m_run[j], tm[j]);
      float p[4];
      float sc = 1.f, lsum = 0.f;
      if (mn > NEG_INF) {
        sc = expf(m_run[j] - mn);
#pragma unroll
        for (int nb = 0; nb < 4; ++nb) p[nb] = expf(vals[nb][j] - mn);
        lsum = p[0] + p[1] + p[2] + p[3];
      } else {
#pragma unroll
        for (int nb = 0; nb < 4; ++nb) p[nb] = 0.f;
      }
#pragma unroll
      for (int o = 1; o < 16; o <<= 1) lsum += __shfl_xor(lsum, o);
      m_run[j] = mn;
      l_run[j] = l_run[j] * sc + lsum;
#pragma unroll
      for (int nb = 0; nb < 4; ++nb) {
        float pg = p[nb] * garow[nb * 16 + qr];
        *(u16*)(ptrow + (((nb * 16 + qr) * 2) ^ psw)) = f2bf(pg);
        oacc[nb][j] *= sc;
      }
    }
#pragma unroll
    for (int ks = 0; ks < 2; ++ks) {
      int kb = (ks * 64 + ((l >> 4) << 4)) ^ sw;
      bfrag pa = *(const bfrag*)((const char*)Pt + (wid * 16 + qr) * 128 + kb);
#pragma unroll
      for (int nb = 0; nb < 4; ++nb) {
        bfrag vv = *(const bfrag*)((const char*)Vt[buf] + (nb * 16 + qr) * 128 + kb);
        oacc[nb] = __builtin_amdgcn_mfma_f32_16x16x32_bf16(pa, vv, oacc[nb], 0, 0, 0);
      }
    }
    __syncthreads();
    buf ^= 1;
  }
#pragma unroll
  for (int j = 0; j < 4; ++j) {
    int row = rowg0 + j;
    float ir = 1.f / l_run[j];
#pragma unroll
    for (int nb = 0; nb < 4; ++nb) {
      int d = nb * 16 + qr;
      ctx[((size_t)b * S + row) * H + h * 64 + d] = f2bf(oacc[nb][j] * ir);
    }
  }
}

// ---------------- final LayerNorm: bf16 in, fp32 out ----------------
__global__ __launch_bounds__(256) void ln_bf_kernel(
    const u16* __restrict__ x, const float* __restrict__ sc,
    const float* __restrict__ bi, float* __restrict__ y) {
  __shared__ float buf[4];
  size_t row = blockIdx.x;
  uint2 xv = reinterpret_cast<const uint2*>(x + row * H)[threadIdx.x];
  float x0 = bf2f(xv.x & 0xffff), x1 = bf2f(xv.x >> 16);
  float x2 = bf2f(xv.y & 0xffff), x3 = bf2f(xv.y >> 16);
  float s  = x0 + x1 + x2 + x3;
  float s2 = x0 * x0 + x1 * x1 + x2 * x2 + x3 * x3;
  s  = block_sum256(s, buf);
  s2 = block_sum256(s2, buf);
  float mu  = s * (1.0f / H);
  float var = s2 * (1.0f / H) - mu * mu;
  float inv = rsqrtf(var + LN_EPS);
  const float4 sv = reinterpret_cast<const float4*>(sc)[threadIdx.x];
  const float4 bv = reinterpret_cast<const float4*>(bi)[threadIdx.x];
  float4 o;
  o.x = (x0 - mu) * inv * sv.x + bv.x;
  o.y = (x1 - mu) * inv * sv.y + bv.y;
  o.z = (x2 - mu) * inv * sv.z + bv.z;
  o.w = (x3 - mu) * inv * sv.w + bv.w;
  reinterpret_cast<float4*>(y + row * H)[threadIdx.x] = o;
}

// ---------------- launch ----------------
extern "C" void kernel_launch(void* const* d_in, const int* in_sizes, int n_in,
                              void* d_out, int out_size, void* d_ws, size_t ws_size,
                              hipStream_t stream) {
  const float* hidden = (const float*)d_in[0];
  const float* gp     = (const float*)d_in[1];
  const int*   am     = (const int*)d_in[2];
  const float* Wq = (const float*)d_in[3];  const float* bq = (const float*)d_in[4];
  const float* Wk = (const float*)d_in[5];  const float* bk = (const float*)d_in[6];
  const float* Wv = (const float*)d_in[7];  const float* bv = (const float*)d_in[8];
  const float* gWq = (const float*)d_in[9]; const float* gbq = (const float*)d_in[10];
  const float* gWk = (const float*)d_in[11];const float* gbk = (const float*)d_in[12];
  const float* glns = (const float*)d_in[13]; const float* glnb = (const float*)d_in[14];
  const float* Wo = (const float*)d_in[15]; const float* bo = (const float*)d_in[16];
  const float* olns = (const float*)d_in[17]; const float* olnb = (const float*)d_in[18];

  float* out    = (float*)d_out;
  float* scores = out + (size_t)BB * S * H;
  float* gattn  = scores + (size_t)BB * NHD * S * S;
  float* brk    = gattn + (size_t)BB * S * S;

  const size_t MB = 1u << 20;
  char* w = (char*)d_ws;
  u16* Wcat  = (u16*)(w);            // 10 MB  [Wq|Wk|Wv|gWq|gWk]
  u16* hbf   = (u16*)(w + 10 * MB);  // 8 MB ; reused as ctxbf after mega-GEMM
  u16* ctxbf = hbf;
  u16* hsbf  = (u16*)(w + 18 * MB);  // 8 MB ; reused as Wobf after mega-GEMM
  u16* Wobf  = hsbf;
  u16* qbf   = (u16*)(w + 26 * MB);  // 8 MB
  u16* kbf   = (u16*)(w + 34 * MB);  // 8 MB
  u16* vtb   = (u16*)(w + 42 * MB);  // 8 MB (V transposed, written by mega-GEMM)
  u16* gqbf  = (u16*)(w + 50 * MB);  // 8 MB ; reused as densebf after band_dots
  u16* densebf = gqbf;
  u16* gkbf  = (u16*)(w + 58 * MB);  // 8 MB
  u32* amb   = (u32*)(w + 66 * MB);  // 512 KB
  float* znext  = (float*)(w + 66 * MB + 512 * 1024);
  float* zprev  = znext + BB * S;
  float* sbandA = zprev + BB * S;
  float* CpreA  = sbandA + BB * S;

  dim3 blk(256);

  // prep: cast 5 weights + hidden (into Wcat..hbf contiguous), mask pack, group-LN
  prep_kernel<<<29696, blk, 0, stream>>>(Wq, Wk, Wv, gWq, gWk, hidden, am,
                                         glns, glnb, Wcat, amb, hsbf);

  // all 5 projections in one GEMM (v written transposed)
  mega_gemm<<<dim3(40, 32), blk, 0, stream>>>(hbf, hsbf, Wcat,
                                              bq, bk, bv, gbq, gbk,
                                              qbf, kbf, vtb, gqbf, gkbf);
  cast_wo_kernel<<<1024, blk, 0, stream>>>(Wo, Wobf);

  // group attention band path
  band_dots_kernel<<<BB * S, blk, 0, stream>>>(gqbf, gkbf, znext, zprev);
  band_prefix_kernel<<<BB, 1024, 0, stream>>>(znext, zprev, am, gp, sbandA, CpreA);
  gattn_write_kernel<<<BB * S, blk, 0, stream>>>(gp, sbandA, CpreA, gattn, brk);

  // fused attention
  flash_kernel<<<dim3(16, 64), blk, 0, stream>>>(qbf, kbf, vtb, amb, gattn, scores, ctxbf);

  // output projection + residual + LN
  gemm_dense<<<dim3(8, 32), blk, 0, stream>>>(ctxbf, Wobf, bo, hidden, densebf);
  ln_bf_kernel<<<BB * S, blk, 0, stream>>>(densebf, olns, olnb, out);
}